// Round 1
// baseline (2554.579 us; speedup 1.0000x reference)
//
#include <hip/hip_runtime.h>
#include <math.h>

// Dims (fixed by the problem)
#define L_ 384
#define R_ 128
#define D_ 128
#define H_ 8
#define DH_ 64
#define DP_ 128
#define INNER_ 512

__device__ __forceinline__ float wred_sum(float v) {
#pragma unroll
  for (int o = 32; o > 0; o >>= 1) v += __shfl_xor(v, o, 64);
  return v;
}
__device__ __forceinline__ float wred_max(float v) {
#pragma unroll
  for (int o = 32; o > 0; o >>= 1) v = fmaxf(v, __shfl_xor(v, o, 64));
  return v;
}

// ---------------------------------------------------------------------------
// Generic 64x64 tile fp32 GEMM, BK=64, 256 threads, 4x4 micro-tile.
// MODE 0: PROJ_W  (A = m gathered as (l,r) rows; C scatter -> qw/kw/vw w-layout)
// MODE 1: PROJ_H  (A = m gathered as (r,l) rows; C scatter -> qh/kh/vh h-layout)
// MODE 2: DOTS    (NT GEMM, A=qh scaled by w_tie on load, C += 0.125*acc)
// MODE 3: OH      (NN GEMM attn @ vh, per-h batch via blockIdx.z)
// MODE 4: OUT_W   (NN, C = 0.5*(acc + bias), scatter to out[r][l][:])
// MODE 5: OUT_H   (NN, A gathered from oh, C += 0.5*(acc + bias))
// MODE 6: plain NN + bias (ks / qs projections)
// ---------------------------------------------------------------------------
template <int MODE>
__global__ __launch_bounds__(256) void gemm_k(
    const float* __restrict__ A, const float* __restrict__ B,
    const float* __restrict__ B2, const float* __restrict__ bias,
    const float* __restrict__ tie, float* __restrict__ C,
    float* __restrict__ C2, float* __restrict__ C3,
    int K, int chunk0, int nBase, int Rc) {
  __shared__ float As[64][68];  // k-major, padded
  __shared__ float Bs[64][68];  // k-major, padded
  const int t = threadIdx.x;
  const int tx = t & 15, ty = t >> 4;
  const int n0 = nBase + blockIdx.x * 64;
  const int m0row = blockIdx.y * 64;
  const int bz = blockIdx.z;

  float acc[4][4] = {};

  for (int k0 = 0; k0 < K; k0 += 64) {
    // ---- load A tile (transpose to k-major) ----
#pragma unroll
    for (int u = 0; u < 4; ++u) {
      int f = t + 256 * u;
      int mr = f >> 4;
      int kq = (f & 15) << 2;
      int p = m0row + mr;
      const float* ap;
      if (MODE == 0) {
        int lrel = p >> 7, rr = p & 127;
        ap = A + ((size_t)(rr * L_ + chunk0 + lrel)) * D_ + k0 + kq;
      } else if (MODE == 1) {
        int rrel = p / L_, l = p - rrel * L_;
        ap = A + ((size_t)((chunk0 + rrel) * L_ + l)) * D_ + k0 + kq;
      } else if (MODE == 2) {
        ap = A + ((size_t)(bz * L_ + p)) * K + k0 + kq;
      } else if (MODE == 3) {
        ap = A + ((size_t)(bz * L_ + p)) * L_ + k0 + kq;
      } else if (MODE == 4) {
        ap = A + (size_t)p * INNER_ + k0 + kq;
      } else if (MODE == 5) {
        int rrel = p / L_, l = p - rrel * L_;
        ap = A + (((size_t)((k0 >> 6) * L_ + l)) * Rc + rrel) * 64 + kq;
      } else {
        ap = A + (size_t)p * 128 + k0 + kq;
      }
      float4 v = *(const float4*)ap;
      if (MODE == 2) {
        float tw = tie[((size_t)p * H_ + bz) * R_ + chunk0 + ((k0 + kq) >> 6)];
        v.x *= tw; v.y *= tw; v.z *= tw; v.w *= tw;
      }
      As[kq + 0][mr] = v.x;
      As[kq + 1][mr] = v.y;
      As[kq + 2][mr] = v.z;
      As[kq + 3][mr] = v.w;
    }
    // ---- load B tile ----
#pragma unroll
    for (int u = 0; u < 4; ++u) {
      int f = t + 256 * u;
      if (MODE == 2) {  // NT: B rows are k-contiguous, transpose on write
        int jr = f >> 4, kq = (f & 15) << 2;
        const float* bp = B + ((size_t)(bz * L_ + n0 + jr)) * K + k0 + kq;
        float4 v = *(const float4*)bp;
        Bs[kq + 0][jr] = v.x;
        Bs[kq + 1][jr] = v.y;
        Bs[kq + 2][jr] = v.z;
        Bs[kq + 3][jr] = v.w;
      } else {
        int kr = f >> 4, nq = (f & 15) << 2;
        int kg = k0 + kr;
        const float* bp;
        if (MODE == 0 || MODE == 1) {
          bp = (n0 < 512) ? (B + (size_t)kg * 512 + n0 + nq)
                          : (B2 + (size_t)kg * 1024 + (n0 - 512) + nq);
        } else if (MODE == 3) {
          bp = B + ((size_t)(bz * L_ + kg)) * ((size_t)Rc * 64) + n0 + nq;
        } else {
          bp = B + (size_t)kg * 128 + n0 + nq;
        }
        *(float4*)&Bs[kr][nq] = *(const float4*)bp;
      }
    }
    __syncthreads();
#pragma unroll
    for (int kk = 0; kk < 64; ++kk) {
      float4 a = *(const float4*)&As[kk][ty << 2];
      float4 b = *(const float4*)&Bs[kk][tx << 2];
      acc[0][0] = fmaf(a.x, b.x, acc[0][0]);
      acc[0][1] = fmaf(a.x, b.y, acc[0][1]);
      acc[0][2] = fmaf(a.x, b.z, acc[0][2]);
      acc[0][3] = fmaf(a.x, b.w, acc[0][3]);
      acc[1][0] = fmaf(a.y, b.x, acc[1][0]);
      acc[1][1] = fmaf(a.y, b.y, acc[1][1]);
      acc[1][2] = fmaf(a.y, b.z, acc[1][2]);
      acc[1][3] = fmaf(a.y, b.w, acc[1][3]);
      acc[2][0] = fmaf(a.z, b.x, acc[2][0]);
      acc[2][1] = fmaf(a.z, b.y, acc[2][1]);
      acc[2][2] = fmaf(a.z, b.z, acc[2][2]);
      acc[2][3] = fmaf(a.z, b.w, acc[2][3]);
      acc[3][0] = fmaf(a.w, b.x, acc[3][0]);
      acc[3][1] = fmaf(a.w, b.y, acc[3][1]);
      acc[3][2] = fmaf(a.w, b.z, acc[3][2]);
      acc[3][3] = fmaf(a.w, b.w, acc[3][3]);
    }
    __syncthreads();
  }

  // ---- epilogue ----
#pragma unroll
  for (int i = 0; i < 4; ++i) {
    int p = m0row + (ty << 2) + i;
    int n = n0 + (tx << 2);
    float4 r;
    r.x = acc[i][0]; r.y = acc[i][1]; r.z = acc[i][2]; r.w = acc[i][3];
    if (MODE == 0 || MODE == 1) {
      float* buf = (n < 512) ? C : (n < 1024 ? C2 : C3);
      int nn = n & 511;
      int h = nn >> 6, dh = nn & 63;
      float* ptr;
      if (MODE == 0) {
        int lrel = p >> 7, rr = p & 127;
        ptr = buf + (((size_t)(lrel * H_ + h)) * R_ + rr) * DH_ + dh;
      } else {
        int rrel = p / L_, l = p - rrel * L_;
        ptr = buf + (((size_t)(h * L_ + l)) * Rc + rrel) * DH_ + dh;
      }
      *(float4*)ptr = r;
    } else if (MODE == 2) {
      float* ptr = C + ((size_t)(bz * L_ + p)) * L_ + n;
      float4 old = *(float4*)ptr;
      old.x += 0.125f * r.x; old.y += 0.125f * r.y;
      old.z += 0.125f * r.z; old.w += 0.125f * r.w;
      *(float4*)ptr = old;
    } else if (MODE == 3) {
      float* ptr = C + ((size_t)(bz * L_ + p)) * ((size_t)Rc * 64) + n;
      *(float4*)ptr = r;
    } else if (MODE == 4) {
      int lrel = p >> 7, rr = p & 127;
      int l = chunk0 + lrel;
      float* ptr = C + ((size_t)(rr * L_ + l)) * D_ + n;
      float4 bb = *(const float4*)&bias[n];
      r.x = 0.5f * (r.x + bb.x); r.y = 0.5f * (r.y + bb.y);
      r.z = 0.5f * (r.z + bb.z); r.w = 0.5f * (r.w + bb.w);
      *(float4*)ptr = r;
    } else if (MODE == 5) {
      int rrel = p / L_, l = p - rrel * L_;
      int rr = chunk0 + rrel;
      float* ptr = C + ((size_t)(rr * L_ + l)) * D_ + n;
      float4 bb = *(const float4*)&bias[n];
      float4 old = *(float4*)ptr;
      old.x += 0.5f * (r.x + bb.x); old.y += 0.5f * (r.y + bb.y);
      old.z += 0.5f * (r.z + bb.z); old.w += 0.5f * (r.w + bb.w);
      *(float4*)ptr = old;
    } else {
      float* ptr = C + (size_t)p * 128 + n;
      float4 bb = *(const float4*)&bias[n];
      r.x += bb.x; r.y += bb.y; r.z += bb.z; r.w += bb.w;
      *(float4*)ptr = r;
    }
  }
}

// ---------------------------------------------------------------------------
// tie softmax: per (l,h): logits[r] = qs[l,h,:16] . ks[r,l,h,:16] / 4 -> softmax over r
// ---------------------------------------------------------------------------
__global__ __launch_bounds__(128) void tie_kernel(const float* __restrict__ qs,
                                                  const float* __restrict__ ks,
                                                  float* __restrict__ wtie) {
  int bid = blockIdx.x;
  int l = bid >> 3, h = bid & 7;
  int r = threadIdx.x;
  int wid = r >> 6;
  const float* qp = qs + (size_t)l * 128 + h * 16;
  const float* kp = ks + ((size_t)r * L_ + l) * 128 + h * 16;
  float s = 0.f;
#pragma unroll
  for (int i = 0; i < 16; ++i) s += qp[i] * kp[i];
  s *= 0.25f;
  __shared__ float sm[2], ss[2];
  float wm = wred_max(s);
  if ((r & 63) == 0) sm[wid] = wm;
  __syncthreads();
  float mx = fmaxf(sm[0], sm[1]);
  float e = __expf(s - mx);
  float wsum = wred_sum(e);
  if ((r & 63) == 0) ss[wid] = wsum;
  __syncthreads();
  float tot = ss[0] + ss[1];
  wtie[((size_t)l * H_ + h) * R_ + r] = e / tot;
}

// ---------------------------------------------------------------------------
// pair layernorm + Wpair -> initialize dots[h][i][j] with the pair bias
// one wave per (i,j), 4 waves / block
// ---------------------------------------------------------------------------
__global__ __launch_bounds__(256) void lnpb_kernel(const float* __restrict__ pair,
                                                   const float* __restrict__ g,
                                                   const float* __restrict__ b,
                                                   const float* __restrict__ wp,
                                                   float* __restrict__ dots) {
  int wid = threadIdx.x >> 6, lane = threadIdx.x & 63;
  int pid = blockIdx.x * 4 + wid;  // < L*L = 147456
  const float* xp = pair + (size_t)pid * DP_ + lane * 2;
  float2 x = *(const float2*)xp;
  float mu = wred_sum(x.x + x.y) * (1.0f / 128.0f);
  float d0 = x.x - mu, d1 = x.y - mu;
  float var = wred_sum(d0 * d0 + d1 * d1) * (1.0f / 128.0f);
  float rs = 1.0f / sqrtf(var + 1e-5f);
  float y0 = d0 * rs * g[lane * 2] + b[lane * 2];
  float y1 = d1 * rs * g[lane * 2 + 1] + b[lane * 2 + 1];
  float ph[8];
#pragma unroll
  for (int h = 0; h < 8; ++h)
    ph[h] = y0 * wp[lane * 16 + h] + y1 * wp[lane * 16 + 8 + h];
#pragma unroll
  for (int h = 0; h < 8; ++h) ph[h] = wred_sum(ph[h]);
  if (lane < 8) dots[(size_t)lane * (L_ * L_) + pid] = ph[lane];
}

// ---------------------------------------------------------------------------
// softmax over last dim (384) of dots (in place), one block per (h,i) row
// ---------------------------------------------------------------------------
__global__ __launch_bounds__(128) void sm_kernel(float* __restrict__ dots) {
  size_t row = blockIdx.x;
  float* p = dots + row * L_;
  int t = threadIdx.x;
  int wid = t >> 6;
  float x0 = p[t], x1 = p[t + 128], x2 = p[t + 256];
  __shared__ float sm[2], ss[2];
  float m = wred_max(fmaxf(x0, fmaxf(x1, x2)));
  if ((t & 63) == 0) sm[wid] = m;
  __syncthreads();
  m = fmaxf(sm[0], sm[1]);
  float e0 = __expf(x0 - m), e1 = __expf(x1 - m), e2 = __expf(x2 - m);
  float s = wred_sum(e0 + e1 + e2);
  if ((t & 63) == 0) ss[wid] = s;
  __syncthreads();
  float inv = 1.0f / (ss[0] + ss[1]);
  p[t] = e0 * inv;
  p[t + 128] = e1 * inv;
  p[t + 256] = e2 * inv;
}

// ---------------------------------------------------------------------------
// column attention per (l,h): S = q k^T * 0.125, softmax rows, O = S v
// flash-style online softmax; thread pair (2t,2t+1) owns row r = t, dh halves
// ---------------------------------------------------------------------------
__global__ __launch_bounds__(256) void attw_kernel(const float* __restrict__ qb,
                                                   const float* __restrict__ kb,
                                                   const float* __restrict__ vb,
                                                   float* __restrict__ ob) {
  __shared__ float Ks[128][64];
  __shared__ float Vs[128][64];
  int bid = blockIdx.x;
  int lrel = bid >> 3, h = bid & 7;
  size_t base = (size_t)(lrel * H_ + h) * R_ * DH_;
  int t = threadIdx.x;
  for (int f = t; f < 2048; f += 256) {
    int row = f >> 4, c = (f & 15) << 2;
    *(float4*)&Ks[row][c] = *(const float4*)&kb[base + (size_t)row * 64 + c];
    *(float4*)&Vs[row][c] = *(const float4*)&vb[base + (size_t)row * 64 + c];
  }
  int r = t >> 1, half = t & 1;
  const float* qp = qb + base + (size_t)r * 64 + half * 32;
  float4 q[8];
#pragma unroll
  for (int i = 0; i < 8; ++i) q[i] = *(const float4*)&qp[i * 4];
  __syncthreads();
  float4 acc[8];
#pragma unroll
  for (int i = 0; i < 8; ++i) acc[i] = make_float4(0.f, 0.f, 0.f, 0.f);
  float mrun = -1e30f, lrun = 0.f;
  for (int j = 0; j < 128; ++j) {
    const float* kr = &Ks[j][half * 32];
    float s = 0.f;
#pragma unroll
    for (int i = 0; i < 8; ++i) {
      float4 k4 = *(const float4*)&kr[i * 4];
      s += q[i].x * k4.x + q[i].y * k4.y + q[i].z * k4.z + q[i].w * k4.w;
    }
    s += __shfl_xor(s, 1, 64);
    s *= 0.125f;
    float mn = fmaxf(mrun, s);
    float a = __expf(mrun - mn);
    float pe = __expf(s - mn);
    lrun = lrun * a + pe;
    mrun = mn;
    const float* vr = &Vs[j][half * 32];
#pragma unroll
    for (int i = 0; i < 8; ++i) {
      float4 v4 = *(const float4*)&vr[i * 4];
      acc[i].x = acc[i].x * a + pe * v4.x;
      acc[i].y = acc[i].y * a + pe * v4.y;
      acc[i].z = acc[i].z * a + pe * v4.z;
      acc[i].w = acc[i].w * a + pe * v4.w;
    }
  }
  float inv = 1.0f / lrun;
  float* op = ob + ((size_t)(lrel * R_ + r)) * INNER_ + h * DH_ + half * 32;
#pragma unroll
  for (int i = 0; i < 8; ++i) {
    float4 o = acc[i];
    o.x *= inv; o.y *= inv; o.z *= inv; o.w *= inv;
    *(float4*)&op[i * 4] = o;
  }
}

// ---------------------------------------------------------------------------
extern "C" void kernel_launch(void* const* d_in, const int* in_sizes, int n_in,
                              void* d_out, int out_size, void* d_ws,
                              size_t ws_size, hipStream_t stream) {
  (void)in_sizes; (void)n_in; (void)out_size;
  const float* m = (const float*)d_in[0];
  const float* pair = (const float*)d_in[1];
  const float* Wq_w = (const float*)d_in[2];
  const float* Wkv_w = (const float*)d_in[3];
  const float* Wo_w = (const float*)d_in[4];
  const float* bo_w = (const float*)d_in[5];
  const float* Wq_h = (const float*)d_in[6];
  const float* Wkv_h = (const float*)d_in[7];
  const float* Wo_h = (const float*)d_in[8];
  const float* bo_h = (const float*)d_in[9];
  const float* ln_g = (const float*)d_in[10];
  const float* ln_b = (const float*)d_in[11];
  const float* Wpair = (const float*)d_in[12];
  const float* Wsq = (const float*)d_in[13];
  const float* bsq = (const float*)d_in[14];
  const float* Wsk = (const float*)d_in[15];
  const float* bsk = (const float*)d_in[16];
  float* out = (float*)d_out;
  float* w = (float*)d_ws;

  // pick chunk count so workspace fits: need = 4*BUF + ks + qs + wtie + dots
  int CH = 4;
  while (CH < 32) {
    size_t need = ((size_t)4 * (25165824u / CH) + 7913472u) * sizeof(float);
    if (need <= ws_size) break;
    CH *= 2;
  }
  const int Lc = L_ / CH;  // 96/48/24/12
  const int Rc = R_ / CH;  // 32/16/8/4
  const size_t BUF = 25165824u / CH;

  float* qb = w;
  float* kb = qb + BUF;
  float* vb = kb + BUF;
  float* ob = vb + BUF;
  float* ksb = ob + BUF;            // (R,L,128)   6291456
  float* qsb = ksb + 6291456;       // (L,128)     49152
  float* wtie = qsb + 49152;        // (L,H,R)     393216
  float* dots = wtie + 393216;      // (H,L,L)     1179648

  // tie projections: ks = m0 @ Wsk + bsk ; qs = m0[0] @ Wsq + bsq
  gemm_k<6><<<dim3(2, 768), 256, 0, stream>>>(m, Wsk, nullptr, bsk, nullptr,
                                              ksb, nullptr, nullptr, 128, 0, 0, 0);
  gemm_k<6><<<dim3(2, 6), 256, 0, stream>>>(m, Wsq, nullptr, bsq, nullptr,
                                            qsb, nullptr, nullptr, 128, 0, 0, 0);
  tie_kernel<<<L_ * H_, 128, 0, stream>>>(qsb, ksb, wtie);
  lnpb_kernel<<<(L_ * L_) / 4, 256, 0, stream>>>(pair, ln_g, ln_b, Wpair, dots);

  // ---- column ("width") attention path ----
  for (int c = 0; c < CH; ++c) {
    int l0 = c * Lc;
    gemm_k<0><<<dim3(24, (Lc * R_) / 64), 256, 0, stream>>>(
        m, Wq_w, Wkv_w, nullptr, nullptr, qb, kb, vb, 128, l0, 0, 0);
    attw_kernel<<<Lc * H_, 256, 0, stream>>>(qb, kb, vb, ob);
    gemm_k<4><<<dim3(2, (Lc * R_) / 64), 256, 0, stream>>>(
        ob, Wo_w, nullptr, bo_w, nullptr, out, nullptr, nullptr, 512, l0, 0, 0);
  }

  // ---- tied row ("height") attention: q/k proj + dots accumulation ----
  for (int c = 0; c < CH; ++c) {
    int r0 = c * Rc;
    gemm_k<1><<<dim3(16, (Rc * L_) / 64), 256, 0, stream>>>(
        m, Wq_h, Wkv_h, nullptr, nullptr, qb, kb, vb, 128, r0, 0, Rc);
    gemm_k<2><<<dim3(6, 6, 8), 256, 0, stream>>>(
        qb, kb, nullptr, nullptr, wtie, dots, nullptr, nullptr, Rc * 64, r0, 0, Rc);
  }
  sm_kernel<<<H_ * L_, 128, 0, stream>>>(dots);

  // ---- v proj + oh + output projection ----
  for (int c = 0; c < CH; ++c) {
    int r0 = c * Rc;
    gemm_k<1><<<dim3(8, (Rc * L_) / 64), 256, 0, stream>>>(
        m, Wq_h, Wkv_h, nullptr, nullptr, qb, kb, vb, 128, r0, 1024, Rc);
    gemm_k<3><<<dim3(Rc, 6, 8), 256, 0, stream>>>(
        dots, vb, nullptr, nullptr, nullptr, ob, nullptr, nullptr, 384, r0, 0, Rc);
    gemm_k<5><<<dim3(2, (Rc * L_) / 64), 256, 0, stream>>>(
        ob, Wo_h, nullptr, bo_h, nullptr, out, nullptr, nullptr, 512, r0, 0, Rc);
  }
}

// Round 2
// 891.419 us; speedup vs baseline: 2.8657x; 2.8657x over previous
//
#include <hip/hip_runtime.h>
#include <math.h>

#define L_ 384
#define R_ 128
#define D_ 128
#define H_ 8
#define DH_ 64
#define INNER_ 512

typedef __bf16 bf16x8 __attribute__((ext_vector_type(8)));
typedef __bf16 bf16x4 __attribute__((ext_vector_type(4)));
typedef float f32x4 __attribute__((ext_vector_type(4)));

__device__ __forceinline__ float wred_sum(float v) {
#pragma unroll
  for (int o = 32; o > 0; o >>= 1) v += __shfl_xor(v, o, 64);
  return v;
}
__device__ __forceinline__ float wred_max(float v) {
#pragma unroll
  for (int o = 32; o > 0; o >>= 1) v = fmaxf(v, __shfl_xor(v, o, 64));
  return v;
}

// ---------------------------------------------------------------------------
// fp32 -> bf16 elementwise (8 per thread)
// ---------------------------------------------------------------------------
__global__ __launch_bounds__(256) void cvt_kernel(const float* __restrict__ in,
                                                  __bf16* __restrict__ out, int n8) {
  int i = blockIdx.x * 256 + threadIdx.x;
  if (i >= n8) return;
  float4 a = *(const float4*)(in + (size_t)i * 8);
  float4 b = *(const float4*)(in + (size_t)i * 8 + 4);
  bf16x8 o;
  o[0] = (__bf16)a.x; o[1] = (__bf16)a.y; o[2] = (__bf16)a.z; o[3] = (__bf16)a.w;
  o[4] = (__bf16)b.x; o[5] = (__bf16)b.y; o[6] = (__bf16)b.z; o[7] = (__bf16)b.w;
  *(uint4*)(out + (size_t)i * 8) = __builtin_bit_cast(uint4, o);
}

// ---------------------------------------------------------------------------
// weight transpose+convert: src fp32 [Kdim][Nstride] (cols n_off..) -> dst bf16 [N][Kdim]
// grid: (Ncnt/64, Kdim/64), block 256
// ---------------------------------------------------------------------------
__global__ __launch_bounds__(256) void wt_kernel(const float* __restrict__ src,
                                                 __bf16* __restrict__ dst, int Kdim,
                                                 int Nstride, int n_off) {
  __shared__ float Ls[64 * 65];
  int n0 = blockIdx.x * 64, k0 = blockIdx.y * 64;
  int t = threadIdx.x;
#pragma unroll
  for (int u = 0; u < 4; ++u) {
    int flat = t + 256 * u;
    int kr = flat >> 4, nc = (flat & 15) * 4;
    float4 v = *(const float4*)&src[(size_t)(k0 + kr) * Nstride + n_off + n0 + nc];
    Ls[kr * 65 + nc + 0] = v.x;
    Ls[kr * 65 + nc + 1] = v.y;
    Ls[kr * 65 + nc + 2] = v.z;
    Ls[kr * 65 + nc + 3] = v.w;
  }
  __syncthreads();
#pragma unroll
  for (int u = 0; u < 2; ++u) {
    int flat = t + 256 * u;
    int nr = flat >> 3, kc = (flat & 7) * 8;
    bf16x8 o;
#pragma unroll
    for (int j = 0; j < 8; ++j) o[j] = (__bf16)Ls[(kc + j) * 65 + nr];
    *(uint4*)&dst[(size_t)(n0 + nr) * Kdim + k0 + kc] = __builtin_bit_cast(uint4, o);
  }
}

// ---------------------------------------------------------------------------
// bf16 MFMA GEMM, 128x128 tile, BK=64, 256 threads (4 waves 2x2), 16x16x32 mfma.
// Both operands staged k-contiguous ("NT" form).
// MODE 0: PROJ_W   A=m_bf gathered (l,r), B=WT_w[1536][128], C->q/k/v w-layout bf16
// MODE 1: PROJ_H   A=m_bf gathered (r,l), B=WT_hqk[1024][128], C->qh/kh h-layout bf16
// MODE 2: DOTS     A=qh (tie-scaled), B=kh (both [h][l][K]), split-K=2 -> dots/dots2 fp32
// MODE 3: OH       A=attn_bf[h][l][384], B=vt[h][n][384], C->ob bf16 [h][l][n]
// MODE 4: OUT_W    A=ow[p][512], B=WoT_w[128][512], C=0.5*(acc+bias) -> out fp32
// MODE 5: OUT_H    A=ob gathered, B=WoT_h, C+=0.5*(acc+bias) -> out fp32
// MODE 6: PROJ_VT  A=WT_vh[512][128], B=m_bf rows, C->vt bf16 (transposed v)
// ---------------------------------------------------------------------------
template <int MODE>
__global__ __launch_bounds__(256) void mm_k(
    const __bf16* __restrict__ A, const __bf16* __restrict__ B,
    const float* __restrict__ bias, const float* __restrict__ tie,
    __bf16* __restrict__ O0, __bf16* __restrict__ O1, __bf16* __restrict__ O2,
    float* __restrict__ F0, float* __restrict__ F1,
    int K, int c0, int Rc, int KT, int firstChunk) {
  __shared__ __bf16 As[128 * 72];
  __shared__ __bf16 Bs[128 * 72];
  const int t = threadIdx.x;
  const int lane = t & 63, w = t >> 6;
  const int wm = w >> 1, wn = w & 1;
  const int n0 = blockIdx.x * 128;
  const int m0 = blockIdx.y * 128;
  int h = 0, s = 0, kOff = 0;
  if (MODE == 2) { h = blockIdx.z >> 1; s = blockIdx.z & 1; kOff = s * K; }
  if (MODE == 3) h = blockIdx.z;
  const int bz = blockIdx.z;

  f32x4 acc[4][4];
#pragma unroll
  for (int i = 0; i < 4; ++i)
#pragma unroll
    for (int j = 0; j < 4; ++j) acc[i][j] = (f32x4){0.f, 0.f, 0.f, 0.f};

  for (int k0 = 0; k0 < K; k0 += 64) {
#pragma unroll
    for (int u = 0; u < 4; ++u) {
      int flat = t + 256 * u;
      int row = flat >> 3;
      int c8 = (flat & 7) << 3;
      // ---- A tile ----
      const __bf16* ap;
      int p = m0 + row;
      if (MODE == 0) ap = A + ((size_t)((p & 127) * L_ + c0 + (p >> 7))) * 128 + k0 + c8;
      else if (MODE == 1) ap = A + ((size_t)(c0 * L_ + p)) * 128 + k0 + c8;
      else if (MODE == 2) ap = A + ((size_t)(h * L_ + p)) * KT + kOff + k0 + c8;
      else if (MODE == 3) ap = A + ((size_t)(h * L_ + p)) * L_ + k0 + c8;
      else if (MODE == 4) ap = A + (size_t)p * INNER_ + k0 + c8;
      else if (MODE == 5) {
        int rrel = p / L_, l = p - rrel * L_;
        ap = A + (((size_t)((k0 >> 6) * L_ + l)) * Rc + rrel) * 64 + c8;
      } else ap = A + (size_t)p * 128 + k0 + c8;
      uint4 av = *(const uint4*)ap;
      if (MODE == 2) {
        float tw = tie[((size_t)p * H_ + h) * R_ + c0 + ((kOff + k0 + c8) >> 6)];
        bf16x8 bv = __builtin_bit_cast(bf16x8, av);
#pragma unroll
        for (int j = 0; j < 8; ++j) bv[j] = (__bf16)((float)bv[j] * tw);
        av = __builtin_bit_cast(uint4, bv);
      }
      *(uint4*)&As[row * 72 + c8] = av;
      // ---- B tile ----
      const __bf16* bp;
      int n = n0 + row;
      if (MODE == 0 || MODE == 1) bp = B + (size_t)n * 128 + k0 + c8;
      else if (MODE == 2) bp = B + ((size_t)(h * L_ + n)) * KT + kOff + k0 + c8;
      else if (MODE == 3) bp = B + ((size_t)(h * Rc * 64 + n)) * L_ + k0 + c8;
      else if (MODE == 4 || MODE == 5) bp = B + (size_t)n * INNER_ + k0 + c8;
      else bp = B + ((size_t)((c0 + bz) * L_ + n)) * 128 + k0 + c8;
      *(uint4*)&Bs[row * 72 + c8] = *(const uint4*)bp;
    }
    __syncthreads();
    {
      int lc = lane & 15, q8 = (lane >> 4) << 3;
#pragma unroll
      for (int kt = 0; kt < 2; ++kt) {
        bf16x8 af[4], bfr[4];
#pragma unroll
        for (int i = 0; i < 4; ++i) {
          af[i] = *(const bf16x8*)&As[(wm * 64 + i * 16 + lc) * 72 + kt * 32 + q8];
          bfr[i] = *(const bf16x8*)&Bs[(wn * 64 + i * 16 + lc) * 72 + kt * 32 + q8];
        }
#pragma unroll
        for (int i = 0; i < 4; ++i)
#pragma unroll
          for (int j = 0; j < 4; ++j)
            acc[i][j] = __builtin_amdgcn_mfma_f32_16x16x32_bf16(af[i], bfr[j], acc[i][j], 0, 0, 0);
      }
    }
    __syncthreads();
  }

  // ---- epilogue ----
  int lce = lane & 15, lr4 = (lane >> 4) << 2;
#pragma unroll
  for (int i = 0; i < 4; ++i) {
#pragma unroll
    for (int j = 0; j < 4; ++j) {
#pragma unroll
      for (int g = 0; g < 4; ++g) {
        int pm = m0 + wm * 64 + i * 16 + lr4 + g;
        int pn = n0 + wn * 64 + j * 16 + lce;
        float v = acc[i][j][g];
        if (MODE == 0) {
          __bf16* buf;
          int nn = pn;
          if (nn < 512) buf = O0;
          else if (nn < 1024) { buf = O1; nn -= 512; }
          else { buf = O2; nn -= 1024; }
          int hh = nn >> 6, dh = nn & 63;
          int lrel = pm >> 7, rr = pm & 127;
          buf[(((size_t)(lrel * H_ + hh)) * R_ + rr) * 64 + dh] = (__bf16)v;
        } else if (MODE == 1) {
          __bf16* buf;
          int nn = pn;
          if (nn < 512) buf = O0;
          else { buf = O1; nn -= 512; }
          int hh = nn >> 6, dh = nn & 63;
          int rrel = pm / L_, l = pm - rrel * L_;
          buf[(((size_t)(hh * L_ + l)) * Rc + rrel) * 64 + dh] = (__bf16)v;
        } else if (MODE == 2) {
          float* dst = (s == 0) ? F0 : F1;
          float* ptr = dst + (size_t)h * (L_ * L_) + (size_t)pm * L_ + pn;
          float val = 0.125f * v;
          if (s == 1 && firstChunk) *ptr = val;
          else *ptr += val;
        } else if (MODE == 3) {
          O0[((size_t)(h * L_ + pm)) * ((size_t)Rc * 64) + pn] = (__bf16)v;
        } else if (MODE == 4) {
          int lrel = pm >> 7, rr = pm & 127;
          F0[((size_t)(rr * L_ + c0 + lrel)) * 128 + pn] = 0.5f * (v + bias[pn]);
        } else if (MODE == 5) {
          int rrel = pm / L_, l = pm - rrel * L_;
          float* ptr = F0 + ((size_t)((c0 + rrel) * L_ + l)) * 128 + pn;
          *ptr += 0.5f * (v + bias[pn]);
        } else {
          O0[(((size_t)((pm >> 6) * Rc + bz)) * 64 + (pm & 63)) * (size_t)L_ + pn] = (__bf16)v;
        }
      }
    }
  }
}

// ---------------------------------------------------------------------------
// fp32 NN GEMM + bias (ks/qs projections), 64x64 tile, K=128
// ---------------------------------------------------------------------------
__global__ __launch_bounds__(256) void gemm6_k(const float* __restrict__ A,
                                               const float* __restrict__ B,
                                               const float* __restrict__ bias,
                                               float* __restrict__ C) {
  __shared__ float As[64][68];
  __shared__ float Bs[64][68];
  const int t = threadIdx.x;
  const int tx = t & 15, ty = t >> 4;
  const int n0 = blockIdx.x * 64;
  const int m0 = blockIdx.y * 64;
  float acc[4][4] = {};
  for (int k0 = 0; k0 < 128; k0 += 64) {
#pragma unroll
    for (int u = 0; u < 4; ++u) {
      int f = t + 256 * u;
      int mr = f >> 4, kq = (f & 15) << 2;
      float4 v = *(const float4*)(A + ((size_t)(m0 + mr)) * 128 + k0 + kq);
      As[kq + 0][mr] = v.x; As[kq + 1][mr] = v.y;
      As[kq + 2][mr] = v.z; As[kq + 3][mr] = v.w;
      *(float4*)&Bs[mr][kq] = *(const float4*)(B + (size_t)(k0 + mr) * 128 + n0 + kq);
    }
    __syncthreads();
#pragma unroll
    for (int kk = 0; kk < 64; ++kk) {
      float4 a = *(const float4*)&As[kk][ty << 2];
      float4 b = *(const float4*)&Bs[kk][tx << 2];
      acc[0][0] = fmaf(a.x, b.x, acc[0][0]); acc[0][1] = fmaf(a.x, b.y, acc[0][1]);
      acc[0][2] = fmaf(a.x, b.z, acc[0][2]); acc[0][3] = fmaf(a.x, b.w, acc[0][3]);
      acc[1][0] = fmaf(a.y, b.x, acc[1][0]); acc[1][1] = fmaf(a.y, b.y, acc[1][1]);
      acc[1][2] = fmaf(a.y, b.z, acc[1][2]); acc[1][3] = fmaf(a.y, b.w, acc[1][3]);
      acc[2][0] = fmaf(a.z, b.x, acc[2][0]); acc[2][1] = fmaf(a.z, b.y, acc[2][1]);
      acc[2][2] = fmaf(a.z, b.z, acc[2][2]); acc[2][3] = fmaf(a.z, b.w, acc[2][3]);
      acc[3][0] = fmaf(a.w, b.x, acc[3][0]); acc[3][1] = fmaf(a.w, b.y, acc[3][1]);
      acc[3][2] = fmaf(a.w, b.z, acc[3][2]); acc[3][3] = fmaf(a.w, b.w, acc[3][3]);
    }
    __syncthreads();
  }
#pragma unroll
  for (int i = 0; i < 4; ++i) {
    int p = m0 + (ty << 2) + i;
    int n = n0 + (tx << 2);
    float4 r;
    r.x = acc[i][0]; r.y = acc[i][1]; r.z = acc[i][2]; r.w = acc[i][3];
    float4 bb = *(const float4*)&bias[n];
    r.x += bb.x; r.y += bb.y; r.z += bb.z; r.w += bb.w;
    *(float4*)(C + (size_t)p * 128 + n) = r;
  }
}

// ---------------------------------------------------------------------------
// tie softmax
// ---------------------------------------------------------------------------
__global__ __launch_bounds__(128) void tie_kernel(const float* __restrict__ qs,
                                                  const float* __restrict__ ks,
                                                  float* __restrict__ wtie) {
  int bid = blockIdx.x;
  int l = bid >> 3, h = bid & 7;
  int r = threadIdx.x;
  int wid = r >> 6;
  const float* qp = qs + (size_t)l * 128 + h * 16;
  const float* kp = ks + ((size_t)r * L_ + l) * 128 + h * 16;
  float s = 0.f;
#pragma unroll
  for (int i = 0; i < 16; ++i) s += qp[i] * kp[i];
  s *= 0.25f;
  __shared__ float sm[2], ss[2];
  float wm = wred_max(s);
  if ((r & 63) == 0) sm[wid] = wm;
  __syncthreads();
  float mx = fmaxf(sm[0], sm[1]);
  float e = __expf(s - mx);
  float wsum = wred_sum(e);
  if ((r & 63) == 0) ss[wid] = wsum;
  __syncthreads();
  float tot = ss[0] + ss[1];
  wtie[((size_t)l * H_ + h) * R_ + r] = e / tot;
}

// ---------------------------------------------------------------------------
// pair LN + Wpair -> dots init with pair bias
// ---------------------------------------------------------------------------
__global__ __launch_bounds__(256) void lnpb_kernel(const float* __restrict__ pair,
                                                   const float* __restrict__ g,
                                                   const float* __restrict__ b,
                                                   const float* __restrict__ wp,
                                                   float* __restrict__ dots) {
  int wid = threadIdx.x >> 6, lane = threadIdx.x & 63;
  int pid = blockIdx.x * 4 + wid;
  const float* xp = pair + (size_t)pid * 128 + lane * 2;
  float2 x = *(const float2*)xp;
  float mu = wred_sum(x.x + x.y) * (1.0f / 128.0f);
  float d0 = x.x - mu, d1 = x.y - mu;
  float var = wred_sum(d0 * d0 + d1 * d1) * (1.0f / 128.0f);
  float rs = 1.0f / sqrtf(var + 1e-5f);
  float y0 = d0 * rs * g[lane * 2] + b[lane * 2];
  float y1 = d1 * rs * g[lane * 2 + 1] + b[lane * 2 + 1];
  float ph[8];
#pragma unroll
  for (int hh = 0; hh < 8; ++hh)
    ph[hh] = y0 * wp[lane * 16 + hh] + y1 * wp[lane * 16 + 8 + hh];
#pragma unroll
  for (int hh = 0; hh < 8; ++hh) ph[hh] = wred_sum(ph[hh]);
  if (lane < 8) dots[(size_t)lane * (L_ * L_) + pid] = ph[lane];
}

// ---------------------------------------------------------------------------
// softmax over last dim of dots+dots2 -> attn bf16
// ---------------------------------------------------------------------------
__global__ __launch_bounds__(128) void sm_kernel(const float* __restrict__ d0,
                                                 const float* __restrict__ d1,
                                                 __bf16* __restrict__ ab) {
  size_t row = blockIdx.x;
  const float* p0 = d0 + row * L_;
  const float* p1 = d1 + row * L_;
  int t = threadIdx.x;
  int wid = t >> 6;
  float x0 = p0[t] + p1[t];
  float x1 = p0[t + 128] + p1[t + 128];
  float x2 = p0[t + 256] + p1[t + 256];
  __shared__ float sm[2], ss[2];
  float m = wred_max(fmaxf(x0, fmaxf(x1, x2)));
  if ((t & 63) == 0) sm[wid] = m;
  __syncthreads();
  m = fmaxf(sm[0], sm[1]);
  float e0 = __expf(x0 - m), e1 = __expf(x1 - m), e2 = __expf(x2 - m);
  float s = wred_sum(e0 + e1 + e2);
  if ((t & 63) == 0) ss[wid] = s;
  __syncthreads();
  float inv = 1.0f / (ss[0] + ss[1]);
  __bf16* op = ab + row * L_;
  op[t] = (__bf16)(e0 * inv);
  op[t + 128] = (__bf16)(e1 * inv);
  op[t + 256] = (__bf16)(e2 * inv);
}

// ---------------------------------------------------------------------------
// column attention (flash, fp32 math, bf16 i/o)
// ---------------------------------------------------------------------------
__global__ __launch_bounds__(256) void attw_kernel(const __bf16* __restrict__ qb,
                                                   const __bf16* __restrict__ kb,
                                                   const __bf16* __restrict__ vb,
                                                   __bf16* __restrict__ ob) {
  __shared__ float Ks[128][64];
  __shared__ float Vs[128][64];
  int bid = blockIdx.x;
  int lrel = bid >> 3, h = bid & 7;
  size_t base = (size_t)(lrel * H_ + h) * (128 * 64);
  int t = threadIdx.x;
#pragma unroll
  for (int u = 0; u < 4; ++u) {
    int flat = t + 256 * u;
    int row = flat >> 3, c8 = (flat & 7) << 3;
    bf16x8 kv = *(const bf16x8*)&kb[base + (size_t)row * 64 + c8];
    bf16x8 vv = *(const bf16x8*)&vb[base + (size_t)row * 64 + c8];
    float4 ka = make_float4((float)kv[0], (float)kv[1], (float)kv[2], (float)kv[3]);
    float4 kbv = make_float4((float)kv[4], (float)kv[5], (float)kv[6], (float)kv[7]);
    float4 va = make_float4((float)vv[0], (float)vv[1], (float)vv[2], (float)vv[3]);
    float4 vbv = make_float4((float)vv[4], (float)vv[5], (float)vv[6], (float)vv[7]);
    *(float4*)&Ks[row][c8] = ka;
    *(float4*)&Ks[row][c8 + 4] = kbv;
    *(float4*)&Vs[row][c8] = va;
    *(float4*)&Vs[row][c8 + 4] = vbv;
  }
  int r = t >> 1, half = t & 1;
  const __bf16* qp = qb + base + (size_t)r * 64 + half * 32;
  float4 q[8];
#pragma unroll
  for (int i = 0; i < 4; ++i) {
    bf16x8 qv = *(const bf16x8*)&qp[i * 8];
    q[2 * i] = make_float4((float)qv[0], (float)qv[1], (float)qv[2], (float)qv[3]);
    q[2 * i + 1] = make_float4((float)qv[4], (float)qv[5], (float)qv[6], (float)qv[7]);
  }
  __syncthreads();
  float4 acc[8];
#pragma unroll
  for (int i = 0; i < 8; ++i) acc[i] = make_float4(0.f, 0.f, 0.f, 0.f);
  float mrun = -1e30f, lrun = 0.f;
  for (int j = 0; j < 128; ++j) {
    const float* kr = &Ks[j][half * 32];
    float s = 0.f;
#pragma unroll
    for (int i = 0; i < 8; ++i) {
      float4 k4 = *(const float4*)&kr[i * 4];
      s += q[i].x * k4.x + q[i].y * k4.y + q[i].z * k4.z + q[i].w * k4.w;
    }
    s += __shfl_xor(s, 1, 64);
    s *= 0.125f;
    float mn = fmaxf(mrun, s);
    float a = __expf(mrun - mn);
    float pe = __expf(s - mn);
    lrun = lrun * a + pe;
    mrun = mn;
    const float* vr = &Vs[j][half * 32];
#pragma unroll
    for (int i = 0; i < 8; ++i) {
      float4 v4 = *(const float4*)&vr[i * 4];
      acc[i].x = acc[i].x * a + pe * v4.x;
      acc[i].y = acc[i].y * a + pe * v4.y;
      acc[i].z = acc[i].z * a + pe * v4.z;
      acc[i].w = acc[i].w * a + pe * v4.w;
    }
  }
  float inv = 1.0f / lrun;
  __bf16* op = ob + ((size_t)(lrel * R_ + r)) * INNER_ + h * 64 + half * 32;
#pragma unroll
  for (int i = 0; i < 8; ++i) {
    bf16x4 ov;
    ov[0] = (__bf16)(acc[i].x * inv);
    ov[1] = (__bf16)(acc[i].y * inv);
    ov[2] = (__bf16)(acc[i].z * inv);
    ov[3] = (__bf16)(acc[i].w * inv);
    *(bf16x4*)&op[i * 4] = ov;
  }
}

// ---------------------------------------------------------------------------
extern "C" void kernel_launch(void* const* d_in, const int* in_sizes, int n_in,
                              void* d_out, int out_size, void* d_ws,
                              size_t ws_size, hipStream_t stream) {
  (void)in_sizes; (void)n_in; (void)out_size;
  const float* m = (const float*)d_in[0];
  const float* pair = (const float*)d_in[1];
  const float* Wq_w = (const float*)d_in[2];
  const float* Wkv_w = (const float*)d_in[3];
  const float* Wo_w = (const float*)d_in[4];
  const float* bo_w = (const float*)d_in[5];
  const float* Wq_h = (const float*)d_in[6];
  const float* Wkv_h = (const float*)d_in[7];
  const float* Wo_h = (const float*)d_in[8];
  const float* bo_h = (const float*)d_in[9];
  const float* ln_g = (const float*)d_in[10];
  const float* ln_b = (const float*)d_in[11];
  const float* Wpair = (const float*)d_in[12];
  const float* Wsq = (const float*)d_in[13];
  const float* bsq = (const float*)d_in[14];
  const float* Wsk = (const float*)d_in[15];
  const float* bsk = (const float*)d_in[16];
  float* out = (float*)d_out;

  // ---- workspace layout ----
  unsigned char* base = (unsigned char*)d_ws;
  __bf16* m_bf = (__bf16*)base;       base += 12582912;   // 6291456 el
  __bf16* WTw = (__bf16*)base;        base += 393216;     // [1536][128]
  __bf16* WThqk = (__bf16*)base;      base += 262144;     // [1024][128]
  __bf16* WTvh = (__bf16*)base;       base += 131072;     // [512][128]
  __bf16* WoTw = (__bf16*)base;       base += 131072;     // [128][512]
  __bf16* WoTh = (__bf16*)base;       base += 131072;
  float* wtie = (float*)base;         base += 1572864;    // (L,H,R) fp32
  float* dots = (float*)base;         base += 4718592;    // (H,L,L) fp32
  float* dots2 = (float*)base;        base += 4718592;
  __bf16* attnb = (__bf16*)base;      base += 2359296;    // (H,L,L) bf16
  float* qsb = (float*)base;          base += 196608;     // (L,128)
  unsigned char* ovl = base;
  float* ksb = (float*)ovl;                               // (R*L,128) fp32 (phase A)

  const size_t fixedB = (size_t)(ovl - (unsigned char*)d_ws);
  int CH = 1;
  for (; CH < 8; CH *= 2) {
    size_t o = 201326592u / CH;
    if (o < 25165824u) o = 25165824u;
    if (fixedB + o <= ws_size) break;
  }
  const int Lc = L_ / CH;
  const int Rc = R_ / CH;
  const size_t BUF = 25165824u / CH;  // elements per buffer
  __bf16* qb = (__bf16*)ovl;
  __bf16* kb = qb + BUF;
  __bf16* vb = kb + BUF;
  __bf16* ob = vb + BUF;

  // ---- convert m + transpose weights to bf16 ----
  cvt_kernel<<<3072, 256, 0, stream>>>(m, m_bf, 786432);
  wt_kernel<<<dim3(8, 2), 256, 0, stream>>>(Wq_w, WTw, 128, 512, 0);
  wt_kernel<<<dim3(16, 2), 256, 0, stream>>>(Wkv_w, WTw + 512 * 128, 128, 1024, 0);
  wt_kernel<<<dim3(8, 2), 256, 0, stream>>>(Wq_h, WThqk, 128, 512, 0);
  wt_kernel<<<dim3(8, 2), 256, 0, stream>>>(Wkv_h, WThqk + 512 * 128, 128, 1024, 0);
  wt_kernel<<<dim3(8, 2), 256, 0, stream>>>(Wkv_h, WTvh, 128, 1024, 512);
  wt_kernel<<<dim3(2, 8), 256, 0, stream>>>(Wo_w, WoTw, 512, 128, 0);
  wt_kernel<<<dim3(2, 8), 256, 0, stream>>>(Wo_h, WoTh, 512, 128, 0);

  // ---- tie path (fp32) + pair bias ----
  gemm6_k<<<dim3(2, 768), 256, 0, stream>>>(m, Wsk, bsk, ksb);
  gemm6_k<<<dim3(2, 6), 256, 0, stream>>>(m, Wsq, bsq, qsb);
  tie_kernel<<<L_ * H_, 128, 0, stream>>>(qsb, ksb, wtie);
  lnpb_kernel<<<(L_ * L_) / 4, 256, 0, stream>>>(pair, ln_g, ln_b, Wpair, dots);

  // ---- column ("width") attention path ----
  for (int c = 0; c < CH; ++c) {
    int l0 = c * Lc;
    mm_k<0><<<dim3(12, Lc), 256, 0, stream>>>(m_bf, WTw, nullptr, nullptr, qb, kb, vb,
                                              nullptr, nullptr, 128, l0, Rc, 0, 0);
    attw_kernel<<<Lc * H_, 256, 0, stream>>>(qb, kb, vb, ob);
    mm_k<4><<<dim3(1, Lc), 256, 0, stream>>>(ob, WoTw, bo_w, nullptr, nullptr, nullptr,
                                             nullptr, out, nullptr, 512, l0, Rc, 0, 0);
  }

  // ---- tied row attention: q/k proj + dots ----
  for (int c = 0; c < CH; ++c) {
    int r0 = c * Rc;
    mm_k<1><<<dim3(8, Rc * 3), 256, 0, stream>>>(m_bf, WThqk, nullptr, nullptr, qb, kb,
                                                 nullptr, nullptr, nullptr, 128, r0, Rc, 0, 0);
    mm_k<2><<<dim3(3, 3, 16), 256, 0, stream>>>(qb, kb, nullptr, wtie, nullptr, nullptr,
                                                nullptr, dots, dots2, Rc * 32, r0, Rc,
                                                Rc * 64, (c == 0) ? 1 : 0);
  }
  sm_kernel<<<H_ * L_, 128, 0, stream>>>(dots, dots2, attnb);

  // ---- v proj (transposed) + oh + output projection ----
  for (int c = 0; c < CH; ++c) {
    int r0 = c * Rc;
    mm_k<6><<<dim3(3, 4, Rc), 256, 0, stream>>>(WTvh, m_bf, nullptr, nullptr, vb, nullptr,
                                                nullptr, nullptr, nullptr, 128, r0, Rc, 0, 0);
    mm_k<3><<<dim3(Rc / 2, 3, 8), 256, 0, stream>>>(attnb, vb, nullptr, nullptr, ob, nullptr,
                                                    nullptr, nullptr, nullptr, 384, r0, Rc, 0, 0);
    mm_k<5><<<dim3(1, Rc * 3), 256, 0, stream>>>(ob, WoTh, bo_h, nullptr, nullptr, nullptr,
                                                 nullptr, out, nullptr, 512, r0, Rc, 0, 0);
  }
}

// Round 3
// 635.951 us; speedup vs baseline: 4.0169x; 1.4017x over previous
//
#include <hip/hip_runtime.h>
#include <math.h>

#define L_ 384
#define R_ 128
#define D_ 128
#define H_ 8
#define DH_ 64
#define INNER_ 512

typedef __bf16 bf16x8 __attribute__((ext_vector_type(8)));
typedef __bf16 bf16x4 __attribute__((ext_vector_type(4)));
typedef float f32x4 __attribute__((ext_vector_type(4)));

__device__ __forceinline__ float wred_sum(float v) {
#pragma unroll
  for (int o = 32; o > 0; o >>= 1) v += __shfl_xor(v, o, 64);
  return v;
}
__device__ __forceinline__ float wred_max(float v) {
#pragma unroll
  for (int o = 32; o > 0; o >>= 1) v = fmaxf(v, __shfl_xor(v, o, 64));
  return v;
}

// ---------------------------------------------------------------------------
// fp32 -> bf16 elementwise (8 per thread)
// ---------------------------------------------------------------------------
__global__ __launch_bounds__(256) void cvt_kernel(const float* __restrict__ in,
                                                  __bf16* __restrict__ out, int n8) {
  int i = blockIdx.x * 256 + threadIdx.x;
  if (i >= n8) return;
  float4 a = *(const float4*)(in + (size_t)i * 8);
  float4 b = *(const float4*)(in + (size_t)i * 8 + 4);
  bf16x8 o;
  o[0] = (__bf16)a.x; o[1] = (__bf16)a.y; o[2] = (__bf16)a.z; o[3] = (__bf16)a.w;
  o[4] = (__bf16)b.x; o[5] = (__bf16)b.y; o[6] = (__bf16)b.z; o[7] = (__bf16)b.w;
  *(uint4*)(out + (size_t)i * 8) = __builtin_bit_cast(uint4, o);
}

// ---------------------------------------------------------------------------
// weight transpose+convert: src fp32 [Kdim][Nstride] (cols n_off..) -> dst bf16 [N][Kdim]
// ---------------------------------------------------------------------------
__global__ __launch_bounds__(256) void wt_kernel(const float* __restrict__ src,
                                                 __bf16* __restrict__ dst, int Kdim,
                                                 int Nstride, int n_off) {
  __shared__ float Ls[64 * 65];
  int n0 = blockIdx.x * 64, k0 = blockIdx.y * 64;
  int t = threadIdx.x;
#pragma unroll
  for (int u = 0; u < 4; ++u) {
    int flat = t + 256 * u;
    int kr = flat >> 4, nc = (flat & 15) * 4;
    float4 v = *(const float4*)&src[(size_t)(k0 + kr) * Nstride + n_off + n0 + nc];
    Ls[kr * 65 + nc + 0] = v.x;
    Ls[kr * 65 + nc + 1] = v.y;
    Ls[kr * 65 + nc + 2] = v.z;
    Ls[kr * 65 + nc + 3] = v.w;
  }
  __syncthreads();
#pragma unroll
  for (int u = 0; u < 2; ++u) {
    int flat = t + 256 * u;
    int nr = flat >> 3, kc = (flat & 7) * 8;
    bf16x8 o;
#pragma unroll
    for (int j = 0; j < 8; ++j) o[j] = (__bf16)Ls[(kc + j) * 65 + nr];
    *(uint4*)&dst[(size_t)(n0 + nr) * Kdim + k0 + kc] = __builtin_bit_cast(uint4, o);
  }
}

// ---------------------------------------------------------------------------
// bf16 MFMA GEMM, 128x128 tile, BK=64, 256 threads (4 waves 2x2), 16x16x32 mfma.
// ---------------------------------------------------------------------------
template <int MODE>
__global__ __launch_bounds__(256) void mm_k(
    const __bf16* __restrict__ A, const __bf16* __restrict__ B,
    const float* __restrict__ bias, const float* __restrict__ tie,
    __bf16* __restrict__ O0, __bf16* __restrict__ O1, __bf16* __restrict__ O2,
    float* __restrict__ F0, float* __restrict__ F1,
    int K, int c0, int Rc, int KT, int firstChunk) {
  __shared__ __bf16 As[128 * 72];
  __shared__ __bf16 Bs[128 * 72];
  const int t = threadIdx.x;
  const int lane = t & 63, w = t >> 6;
  const int wm = w >> 1, wn = w & 1;
  const int n0 = blockIdx.x * 128;
  const int m0 = blockIdx.y * 128;
  int h = 0, s = 0, kOff = 0;
  if (MODE == 2) { h = blockIdx.z >> 1; s = blockIdx.z & 1; kOff = s * K; }
  if (MODE == 3) h = blockIdx.z;
  const int bz = blockIdx.z;

  f32x4 acc[4][4];
#pragma unroll
  for (int i = 0; i < 4; ++i)
#pragma unroll
    for (int j = 0; j < 4; ++j) acc[i][j] = (f32x4){0.f, 0.f, 0.f, 0.f};

  for (int k0 = 0; k0 < K; k0 += 64) {
#pragma unroll
    for (int u = 0; u < 4; ++u) {
      int flat = t + 256 * u;
      int row = flat >> 3;
      int c8 = (flat & 7) << 3;
      const __bf16* ap;
      int p = m0 + row;
      if (MODE == 0) ap = A + ((size_t)((p & 127) * L_ + c0 + (p >> 7))) * 128 + k0 + c8;
      else if (MODE == 1) ap = A + ((size_t)(c0 * L_ + p)) * 128 + k0 + c8;
      else if (MODE == 2) ap = A + ((size_t)(h * L_ + p)) * KT + kOff + k0 + c8;
      else if (MODE == 3) ap = A + ((size_t)(h * L_ + p)) * L_ + k0 + c8;
      else if (MODE == 4) ap = A + (size_t)p * INNER_ + k0 + c8;
      else if (MODE == 5) {
        int rrel = p / L_, l = p - rrel * L_;
        ap = A + (((size_t)((k0 >> 6) * L_ + l)) * Rc + rrel) * 64 + c8;
      } else ap = A + (size_t)p * 128 + k0 + c8;
      uint4 av = *(const uint4*)ap;
      if (MODE == 2) {
        float tw = tie[((size_t)p * H_ + h) * R_ + c0 + ((kOff + k0 + c8) >> 6)];
        bf16x8 bv = __builtin_bit_cast(bf16x8, av);
#pragma unroll
        for (int j = 0; j < 8; ++j) bv[j] = (__bf16)((float)bv[j] * tw);
        av = __builtin_bit_cast(uint4, bv);
      }
      *(uint4*)&As[row * 72 + c8] = av;
      const __bf16* bp;
      int n = n0 + row;
      if (MODE == 0 || MODE == 1) bp = B + (size_t)n * 128 + k0 + c8;
      else if (MODE == 2) bp = B + ((size_t)(h * L_ + n)) * KT + kOff + k0 + c8;
      else if (MODE == 3) bp = B + ((size_t)(h * Rc * 64 + n)) * L_ + k0 + c8;
      else if (MODE == 4 || MODE == 5) bp = B + (size_t)n * INNER_ + k0 + c8;
      else bp = B + ((size_t)((c0 + bz) * L_ + n)) * 128 + k0 + c8;
      *(uint4*)&Bs[row * 72 + c8] = *(const uint4*)bp;
    }
    __syncthreads();
    {
      int lc = lane & 15, q8 = (lane >> 4) << 3;
#pragma unroll
      for (int kt = 0; kt < 2; ++kt) {
        bf16x8 af[4], bfr[4];
#pragma unroll
        for (int i = 0; i < 4; ++i) {
          af[i] = *(const bf16x8*)&As[(wm * 64 + i * 16 + lc) * 72 + kt * 32 + q8];
          bfr[i] = *(const bf16x8*)&Bs[(wn * 64 + i * 16 + lc) * 72 + kt * 32 + q8];
        }
#pragma unroll
        for (int i = 0; i < 4; ++i)
#pragma unroll
          for (int j = 0; j < 4; ++j)
            acc[i][j] = __builtin_amdgcn_mfma_f32_16x16x32_bf16(af[i], bfr[j], acc[i][j], 0, 0, 0);
      }
    }
    __syncthreads();
  }

  int lce = lane & 15, lr4 = (lane >> 4) << 2;
#pragma unroll
  for (int i = 0; i < 4; ++i) {
#pragma unroll
    for (int j = 0; j < 4; ++j) {
#pragma unroll
      for (int g = 0; g < 4; ++g) {
        int pm = m0 + wm * 64 + i * 16 + lr4 + g;
        int pn = n0 + wn * 64 + j * 16 + lce;
        float v = acc[i][j][g];
        if (MODE == 0) {
          __bf16* buf;
          int nn = pn;
          if (nn < 512) buf = O0;
          else if (nn < 1024) { buf = O1; nn -= 512; }
          else { buf = O2; nn -= 1024; }
          int hh = nn >> 6, dh = nn & 63;
          int lrel = pm >> 7, rr = pm & 127;
          buf[(((size_t)(lrel * H_ + hh)) * R_ + rr) * 64 + dh] = (__bf16)v;
        } else if (MODE == 1) {
          __bf16* buf;
          int nn = pn;
          if (nn < 512) buf = O0;
          else { buf = O1; nn -= 512; }
          int hh = nn >> 6, dh = nn & 63;
          int rrel = pm / L_, l = pm - rrel * L_;
          buf[(((size_t)(hh * L_ + l)) * Rc + rrel) * 64 + dh] = (__bf16)v;
        } else if (MODE == 2) {
          float* dst = (s == 0) ? F0 : F1;
          float* ptr = dst + (size_t)h * (L_ * L_) + (size_t)pm * L_ + pn;
          float val = 0.125f * v;
          if (s == 1 && firstChunk) *ptr = val;
          else *ptr += val;
        } else if (MODE == 3) {
          O0[((size_t)(h * L_ + pm)) * ((size_t)Rc * 64) + pn] = (__bf16)v;
        } else if (MODE == 4) {
          int lrel = pm >> 7, rr = pm & 127;
          F0[((size_t)(rr * L_ + c0 + lrel)) * 128 + pn] = 0.5f * (v + bias[pn]);
        } else if (MODE == 5) {
          int rrel = pm / L_, l = pm - rrel * L_;
          float* ptr = F0 + ((size_t)((c0 + rrel) * L_ + l)) * 128 + pn;
          *ptr += 0.5f * (v + bias[pn]);
        } else {
          O0[(((size_t)((pm >> 6) * Rc + bz)) * 64 + (pm & 63)) * (size_t)L_ + pn] = (__bf16)v;
        }
      }
    }
  }
}

// ---------------------------------------------------------------------------
// fp32 NN GEMM + bias (ks/qs projections), 64x64 tile, K=128
// ---------------------------------------------------------------------------
__global__ __launch_bounds__(256) void gemm6_k(const float* __restrict__ A,
                                               const float* __restrict__ B,
                                               const float* __restrict__ bias,
                                               float* __restrict__ C) {
  __shared__ float As[64][68];
  __shared__ float Bs[64][68];
  const int t = threadIdx.x;
  const int tx = t & 15, ty = t >> 4;
  const int n0 = blockIdx.x * 64;
  const int m0 = blockIdx.y * 64;
  float acc[4][4] = {};
  for (int k0 = 0; k0 < 128; k0 += 64) {
#pragma unroll
    for (int u = 0; u < 4; ++u) {
      int f = t + 256 * u;
      int mr = f >> 4, kq = (f & 15) << 2;
      float4 v = *(const float4*)(A + ((size_t)(m0 + mr)) * 128 + k0 + kq);
      As[kq + 0][mr] = v.x; As[kq + 1][mr] = v.y;
      As[kq + 2][mr] = v.z; As[kq + 3][mr] = v.w;
      *(float4*)&Bs[mr][kq] = *(const float4*)(B + (size_t)(k0 + mr) * 128 + n0 + kq);
    }
    __syncthreads();
#pragma unroll
    for (int kk = 0; kk < 64; ++kk) {
      float4 a = *(const float4*)&As[kk][ty << 2];
      float4 b = *(const float4*)&Bs[kk][tx << 2];
      acc[0][0] = fmaf(a.x, b.x, acc[0][0]); acc[0][1] = fmaf(a.x, b.y, acc[0][1]);
      acc[0][2] = fmaf(a.x, b.z, acc[0][2]); acc[0][3] = fmaf(a.x, b.w, acc[0][3]);
      acc[1][0] = fmaf(a.y, b.x, acc[1][0]); acc[1][1] = fmaf(a.y, b.y, acc[1][1]);
      acc[1][2] = fmaf(a.y, b.z, acc[1][2]); acc[1][3] = fmaf(a.y, b.w, acc[1][3]);
      acc[2][0] = fmaf(a.z, b.x, acc[2][0]); acc[2][1] = fmaf(a.z, b.y, acc[2][1]);
      acc[2][2] = fmaf(a.z, b.z, acc[2][2]); acc[2][3] = fmaf(a.z, b.w, acc[2][3]);
      acc[3][0] = fmaf(a.w, b.x, acc[3][0]); acc[3][1] = fmaf(a.w, b.y, acc[3][1]);
      acc[3][2] = fmaf(a.w, b.z, acc[3][2]); acc[3][3] = fmaf(a.w, b.w, acc[3][3]);
    }
    __syncthreads();
  }
#pragma unroll
  for (int i = 0; i < 4; ++i) {
    int p = m0 + (ty << 2) + i;
    int n = n0 + (tx << 2);
    float4 r;
    r.x = acc[i][0]; r.y = acc[i][1]; r.z = acc[i][2]; r.w = acc[i][3];
    float4 bb = *(const float4*)&bias[n];
    r.x += bb.x; r.y += bb.y; r.z += bb.z; r.w += bb.w;
    *(float4*)(C + (size_t)p * 128 + n) = r;
  }
}

// ---------------------------------------------------------------------------
// tie softmax
// ---------------------------------------------------------------------------
__global__ __launch_bounds__(128) void tie_kernel(const float* __restrict__ qs,
                                                  const float* __restrict__ ks,
                                                  float* __restrict__ wtie) {
  int bid = blockIdx.x;
  int l = bid >> 3, h = bid & 7;
  int r = threadIdx.x;
  int wid = r >> 6;
  const float* qp = qs + (size_t)l * 128 + h * 16;
  const float* kp = ks + ((size_t)r * L_ + l) * 128 + h * 16;
  float s = 0.f;
#pragma unroll
  for (int i = 0; i < 16; ++i) s += qp[i] * kp[i];
  s *= 0.25f;
  __shared__ float sm[2], ss[2];
  float wm = wred_max(s);
  if ((r & 63) == 0) sm[wid] = wm;
  __syncthreads();
  float mx = fmaxf(sm[0], sm[1]);
  float e = __expf(s - mx);
  float wsum = wred_sum(e);
  if ((r & 63) == 0) ss[wid] = wsum;
  __syncthreads();
  float tot = ss[0] + ss[1];
  wtie[((size_t)l * H_ + h) * R_ + r] = e / tot;
}

// ---------------------------------------------------------------------------
// pair LN + Wpair -> dots init with pair bias
// ---------------------------------------------------------------------------
__global__ __launch_bounds__(256) void lnpb_kernel(const float* __restrict__ pair,
                                                   const float* __restrict__ g,
                                                   const float* __restrict__ b,
                                                   const float* __restrict__ wp,
                                                   float* __restrict__ dots) {
  int wid = threadIdx.x >> 6, lane = threadIdx.x & 63;
  int pid = blockIdx.x * 4 + wid;
  const float* xp = pair + (size_t)pid * 128 + lane * 2;
  float2 x = *(const float2*)xp;
  float mu = wred_sum(x.x + x.y) * (1.0f / 128.0f);
  float d0 = x.x - mu, d1 = x.y - mu;
  float var = wred_sum(d0 * d0 + d1 * d1) * (1.0f / 128.0f);
  float rs = 1.0f / sqrtf(var + 1e-5f);
  float y0 = d0 * rs * g[lane * 2] + b[lane * 2];
  float y1 = d1 * rs * g[lane * 2 + 1] + b[lane * 2 + 1];
  float ph[8];
#pragma unroll
  for (int hh = 0; hh < 8; ++hh)
    ph[hh] = y0 * wp[lane * 16 + hh] + y1 * wp[lane * 16 + 8 + hh];
#pragma unroll
  for (int hh = 0; hh < 8; ++hh) ph[hh] = wred_sum(ph[hh]);
  if (lane < 8) dots[(size_t)lane * (L_ * L_) + pid] = ph[lane];
}

// ---------------------------------------------------------------------------
// softmax over last dim of dots+dots2 -> attn bf16
// ---------------------------------------------------------------------------
__global__ __launch_bounds__(128) void sm_kernel(const float* __restrict__ d0,
                                                 const float* __restrict__ d1,
                                                 __bf16* __restrict__ ab) {
  size_t row = blockIdx.x;
  const float* p0 = d0 + row * L_;
  const float* p1 = d1 + row * L_;
  int t = threadIdx.x;
  int wid = t >> 6;
  float x0 = p0[t] + p1[t];
  float x1 = p0[t + 128] + p1[t + 128];
  float x2 = p0[t + 256] + p1[t + 256];
  __shared__ float sm[2], ss[2];
  float m = wred_max(fmaxf(x0, fmaxf(x1, x2)));
  if ((t & 63) == 0) sm[wid] = m;
  __syncthreads();
  m = fmaxf(sm[0], sm[1]);
  float e0 = __expf(x0 - m), e1 = __expf(x1 - m), e2 = __expf(x2 - m);
  float s = wred_sum(e0 + e1 + e2);
  if ((t & 63) == 0) ss[wid] = s;
  __syncthreads();
  float inv = 1.0f / (ss[0] + ss[1]);
  __bf16* op = ab + row * L_;
  op[t] = (__bf16)(e0 * inv);
  op[t + 128] = (__bf16)(e1 * inv);
  op[t + 256] = (__bf16)(e2 * inv);
}

// ---------------------------------------------------------------------------
// column attention, MFMA version. One block per (lrel, h); 4 waves.
// S = Q K^T (K=64), row softmax in registers, P via LDS, O = P V (K=128).
// LDS: Qs[128][72] | Ks[128][72] | Vt[64][136]; Ps[128][140] overlaps Qs+Ks.
// ---------------------------------------------------------------------------
__global__ __launch_bounds__(256) void attw_kernel(const __bf16* __restrict__ qb,
                                                   const __bf16* __restrict__ kb,
                                                   const __bf16* __restrict__ vb,
                                                   __bf16* __restrict__ ob) {
  __shared__ __bf16 smem[27136];
  __bf16* Qs = smem;             // 128*72 = 9216
  __bf16* Ks = smem + 9216;      // 9216
  __bf16* Vt = smem + 18432;     // 64*136 = 8704
  __bf16* Ps = smem;             // 128*140 = 17920 (< 18432, overlaps Qs+Ks)
  int bid = blockIdx.x;
  int lrel = bid >> 3, h = bid & 7;
  size_t base = (size_t)(lrel * H_ + h) * (128 * 64);
  int t = threadIdx.x;
  // stage Q, K (k-contiguous, ld 72)
#pragma unroll
  for (int u = 0; u < 4; ++u) {
    int flat = t + 256 * u;
    int row = flat >> 3, c8 = (flat & 7) << 3;
    *(uint4*)&Qs[row * 72 + c8] = *(const uint4*)&qb[base + (size_t)row * 64 + c8];
    *(uint4*)&Ks[row * 72 + c8] = *(const uint4*)&kb[base + (size_t)row * 64 + c8];
  }
  // stage V transposed: Vt[dh][r], ld 136
#pragma unroll
  for (int u = 0; u < 4; ++u) {
    int idx = t + 256 * u;  // 0..1023
    int r = idx & 127, c8 = (idx >> 7) << 3;
    bf16x8 v = *(const bf16x8*)&vb[base + (size_t)r * 64 + c8];
#pragma unroll
    for (int j = 0; j < 8; ++j) Vt[(c8 + j) * 136 + r] = v[j];
  }
  __syncthreads();

  const int lane = t & 63, w = t >> 6;
  const int lc = lane & 15, q8 = (lane >> 4) << 3;

  // ---- S = Q K^T : wave w owns rows [w*32, w*32+32), all 128 cols ----
  f32x4 s[2][8];
#pragma unroll
  for (int i = 0; i < 2; ++i)
#pragma unroll
    for (int n = 0; n < 8; ++n) s[i][n] = (f32x4){0.f, 0.f, 0.f, 0.f};
#pragma unroll
  for (int kt = 0; kt < 2; ++kt) {
    bf16x8 a[2];
#pragma unroll
    for (int i = 0; i < 2; ++i)
      a[i] = *(const bf16x8*)&Qs[(w * 32 + i * 16 + lc) * 72 + kt * 32 + q8];
#pragma unroll
    for (int n = 0; n < 8; ++n) {
      bf16x8 b = *(const bf16x8*)&Ks[(n * 16 + lc) * 72 + kt * 32 + q8];
#pragma unroll
      for (int i = 0; i < 2; ++i)
        s[i][n] = __builtin_amdgcn_mfma_f32_16x16x32_bf16(a[i], b, s[i][n], 0, 0, 0);
    }
  }

  // ---- row softmax in registers (row = w*32 + i*16 + (lane>>4)*4 + g) ----
  float linv[2][4];
#pragma unroll
  for (int i = 0; i < 2; ++i) {
#pragma unroll
    for (int g = 0; g < 4; ++g) {
      float mx = -1e30f;
#pragma unroll
      for (int n = 0; n < 8; ++n) mx = fmaxf(mx, s[i][n][g]);
      mx = fmaxf(mx, __shfl_xor(mx, 1, 64));
      mx = fmaxf(mx, __shfl_xor(mx, 2, 64));
      mx = fmaxf(mx, __shfl_xor(mx, 4, 64));
      mx = fmaxf(mx, __shfl_xor(mx, 8, 64));
      float sum = 0.f;
#pragma unroll
      for (int n = 0; n < 8; ++n) {
        float e = __expf(0.125f * (s[i][n][g] - mx));
        s[i][n][g] = e;
        sum += e;
      }
      sum += __shfl_xor(sum, 1, 64);
      sum += __shfl_xor(sum, 2, 64);
      sum += __shfl_xor(sum, 4, 64);
      sum += __shfl_xor(sum, 8, 64);
      linv[i][g] = 1.0f / sum;
    }
  }
  __syncthreads();  // Q/K reads done; safe to overwrite with P

  // ---- store P to LDS (row-major, ld 140) ----
#pragma unroll
  for (int i = 0; i < 2; ++i)
#pragma unroll
    for (int n = 0; n < 8; ++n)
#pragma unroll
      for (int g = 0; g < 4; ++g) {
        int row = w * 32 + i * 16 + ((lane >> 4) << 2) + g;
        int col = n * 16 + lc;
        Ps[row * 140 + col] = (__bf16)s[i][n][g];
      }
  __syncthreads();

  // ---- O = P V : wave w rows [w*32, w*32+32), 64 cols, K=128 ----
  f32x4 o[2][4];
#pragma unroll
  for (int i = 0; i < 2; ++i)
#pragma unroll
    for (int n = 0; n < 4; ++n) o[i][n] = (f32x4){0.f, 0.f, 0.f, 0.f};
#pragma unroll
  for (int kt = 0; kt < 4; ++kt) {
    bf16x8 a[2];
#pragma unroll
    for (int i = 0; i < 2; ++i)
      a[i] = *(const bf16x8*)&Ps[(w * 32 + i * 16 + lc) * 140 + kt * 32 + q8];
#pragma unroll
    for (int n = 0; n < 4; ++n) {
      bf16x8 b = *(const bf16x8*)&Vt[(n * 16 + lc) * 136 + kt * 32 + q8];
#pragma unroll
      for (int i = 0; i < 2; ++i)
        o[i][n] = __builtin_amdgcn_mfma_f32_16x16x32_bf16(a[i], b, o[i][n], 0, 0, 0);
    }
  }

  // ---- epilogue: scale by 1/l, write to ob[(lrel*R + r)*512 + h*64 + dh] ----
#pragma unroll
  for (int i = 0; i < 2; ++i)
#pragma unroll
    for (int n = 0; n < 4; ++n)
#pragma unroll
      for (int g = 0; g < 4; ++g) {
        int r = w * 32 + i * 16 + ((lane >> 4) << 2) + g;
        int dh = n * 16 + lc;
        ob[((size_t)(lrel * R_ + r)) * INNER_ + h * 64 + dh] =
            (__bf16)(o[i][n][g] * linv[i][g]);
      }
}

// ---------------------------------------------------------------------------
extern "C" void kernel_launch(void* const* d_in, const int* in_sizes, int n_in,
                              void* d_out, int out_size, void* d_ws,
                              size_t ws_size, hipStream_t stream) {
  (void)in_sizes; (void)n_in; (void)out_size;
  const float* m = (const float*)d_in[0];
  const float* pair = (const float*)d_in[1];
  const float* Wq_w = (const float*)d_in[2];
  const float* Wkv_w = (const float*)d_in[3];
  const float* Wo_w = (const float*)d_in[4];
  const float* bo_w = (const float*)d_in[5];
  const float* Wq_h = (const float*)d_in[6];
  const float* Wkv_h = (const float*)d_in[7];
  const float* Wo_h = (const float*)d_in[8];
  const float* bo_h = (const float*)d_in[9];
  const float* ln_g = (const float*)d_in[10];
  const float* ln_b = (const float*)d_in[11];
  const float* Wpair = (const float*)d_in[12];
  const float* Wsq = (const float*)d_in[13];
  const float* bsq = (const float*)d_in[14];
  const float* Wsk = (const float*)d_in[15];
  const float* bsk = (const float*)d_in[16];
  float* out = (float*)d_out;

  unsigned char* base = (unsigned char*)d_ws;
  __bf16* m_bf = (__bf16*)base;       base += 12582912;
  __bf16* WTw = (__bf16*)base;        base += 393216;
  __bf16* WThqk = (__bf16*)base;      base += 262144;
  __bf16* WTvh = (__bf16*)base;       base += 131072;
  __bf16* WoTw = (__bf16*)base;       base += 131072;
  __bf16* WoTh = (__bf16*)base;       base += 131072;
  float* wtie = (float*)base;         base += 1572864;
  float* dots = (float*)base;         base += 4718592;
  float* dots2 = (float*)base;        base += 4718592;
  __bf16* attnb = (__bf16*)base;      base += 2359296;
  float* qsb = (float*)base;          base += 196608;
  unsigned char* ovl = base;
  float* ksb = (float*)ovl;

  const size_t fixedB = (size_t)(ovl - (unsigned char*)d_ws);
  int CH = 1;
  for (; CH < 8; CH *= 2) {
    size_t o = 201326592u / CH;
    if (o < 25165824u) o = 25165824u;
    if (fixedB + o <= ws_size) break;
  }
  const int Lc = L_ / CH;
  const int Rc = R_ / CH;
  const size_t BUF = 25165824u / CH;
  __bf16* qb = (__bf16*)ovl;
  __bf16* kb = qb + BUF;
  __bf16* vb = kb + BUF;
  __bf16* ob = vb + BUF;

  cvt_kernel<<<3072, 256, 0, stream>>>(m, m_bf, 786432);
  wt_kernel<<<dim3(8, 2), 256, 0, stream>>>(Wq_w, WTw, 128, 512, 0);
  wt_kernel<<<dim3(16, 2), 256, 0, stream>>>(Wkv_w, WTw + 512 * 128, 128, 1024, 0);
  wt_kernel<<<dim3(8, 2), 256, 0, stream>>>(Wq_h, WThqk, 128, 512, 0);
  wt_kernel<<<dim3(8, 2), 256, 0, stream>>>(Wkv_h, WThqk + 512 * 128, 128, 1024, 0);
  wt_kernel<<<dim3(8, 2), 256, 0, stream>>>(Wkv_h, WTvh, 128, 1024, 512);
  wt_kernel<<<dim3(2, 8), 256, 0, stream>>>(Wo_w, WoTw, 512, 128, 0);
  wt_kernel<<<dim3(2, 8), 256, 0, stream>>>(Wo_h, WoTh, 512, 128, 0);

  gemm6_k<<<dim3(2, 768), 256, 0, stream>>>(m, Wsk, bsk, ksb);
  gemm6_k<<<dim3(2, 6), 256, 0, stream>>>(m, Wsq, bsq, qsb);
  tie_kernel<<<L_ * H_, 128, 0, stream>>>(qsb, ksb, wtie);
  lnpb_kernel<<<(L_ * L_) / 4, 256, 0, stream>>>(pair, ln_g, ln_b, Wpair, dots);

  for (int c = 0; c < CH; ++c) {
    int l0 = c * Lc;
    mm_k<0><<<dim3(12, Lc), 256, 0, stream>>>(m_bf, WTw, nullptr, nullptr, qb, kb, vb,
                                              nullptr, nullptr, 128, l0, Rc, 0, 0);
    attw_kernel<<<Lc * H_, 256, 0, stream>>>(qb, kb, vb, ob);
    mm_k<4><<<dim3(1, Lc), 256, 0, stream>>>(ob, WoTw, bo_w, nullptr, nullptr, nullptr,
                                             nullptr, out, nullptr, 512, l0, Rc, 0, 0);
  }

  for (int c = 0; c < CH; ++c) {
    int r0 = c * Rc;
    mm_k<1><<<dim3(8, Rc * 3), 256, 0, stream>>>(m_bf, WThqk, nullptr, nullptr, qb, kb,
                                                 nullptr, nullptr, nullptr, 128, r0, Rc, 0, 0);
    mm_k<2><<<dim3(3, 3, 16), 256, 0, stream>>>(qb, kb, nullptr, wtie, nullptr, nullptr,
                                                nullptr, dots, dots2, Rc * 32, r0, Rc,
                                                Rc * 64, (c == 0) ? 1 : 0);
  }
  sm_kernel<<<H_ * L_, 128, 0, stream>>>(dots, dots2, attnb);

  for (int c = 0; c < CH; ++c) {
    int r0 = c * Rc;
    mm_k<6><<<dim3(3, 4, Rc), 256, 0, stream>>>(WTvh, m_bf, nullptr, nullptr, vb, nullptr,
                                                nullptr, nullptr, nullptr, 128, r0, Rc, 0, 0);
    mm_k<3><<<dim3(Rc / 2, 3, 8), 256, 0, stream>>>(attnb, vb, nullptr, nullptr, ob, nullptr,
                                                    nullptr, nullptr, nullptr, 384, r0, Rc, 0, 0);
    mm_k<5><<<dim3(1, Rc * 3), 256, 0, stream>>>(ob, WoTh, bo_h, nullptr, nullptr, nullptr,
                                                 nullptr, out, nullptr, 512, r0, Rc, 0, 0);
  }
}

// Round 4
// 614.475 us; speedup vs baseline: 4.1573x; 1.0350x over previous
//
#include <hip/hip_runtime.h>
#include <math.h>

#define L_ 384
#define R_ 128
#define D_ 128
#define H_ 8
#define DH_ 64
#define INNER_ 512

typedef __bf16 bf16x8 __attribute__((ext_vector_type(8)));
typedef __bf16 bf16x4 __attribute__((ext_vector_type(4)));
typedef float f32x4 __attribute__((ext_vector_type(4)));

__device__ __forceinline__ float wred_sum(float v) {
#pragma unroll
  for (int o = 32; o > 0; o >>= 1) v += __shfl_xor(v, o, 64);
  return v;
}
__device__ __forceinline__ float wred_max(float v) {
#pragma unroll
  for (int o = 32; o > 0; o >>= 1) v = fmaxf(v, __shfl_xor(v, o, 64));
  return v;
}

// ---------------------------------------------------------------------------
// fp32 -> bf16 elementwise (8 per thread)
// ---------------------------------------------------------------------------
__global__ __launch_bounds__(256) void cvt_kernel(const float* __restrict__ in,
                                                  __bf16* __restrict__ out, int n8) {
  int i = blockIdx.x * 256 + threadIdx.x;
  if (i >= n8) return;
  float4 a = *(const float4*)(in + (size_t)i * 8);
  float4 b = *(const float4*)(in + (size_t)i * 8 + 4);
  bf16x8 o;
  o[0] = (__bf16)a.x; o[1] = (__bf16)a.y; o[2] = (__bf16)a.z; o[3] = (__bf16)a.w;
  o[4] = (__bf16)b.x; o[5] = (__bf16)b.y; o[6] = (__bf16)b.z; o[7] = (__bf16)b.w;
  *(uint4*)(out + (size_t)i * 8) = __builtin_bit_cast(uint4, o);
}

// ---------------------------------------------------------------------------
// weight transpose+convert: src fp32 [Kdim][Nstride] (cols n_off..) -> dst bf16 [N][Kdim]
// ---------------------------------------------------------------------------
__global__ __launch_bounds__(256) void wt_kernel(const float* __restrict__ src,
                                                 __bf16* __restrict__ dst, int Kdim,
                                                 int Nstride, int n_off) {
  __shared__ float Ls[64 * 65];
  int n0 = blockIdx.x * 64, k0 = blockIdx.y * 64;
  int t = threadIdx.x;
#pragma unroll
  for (int u = 0; u < 4; ++u) {
    int flat = t + 256 * u;
    int kr = flat >> 4, nc = (flat & 15) * 4;
    float4 v = *(const float4*)&src[(size_t)(k0 + kr) * Nstride + n_off + n0 + nc];
    Ls[kr * 65 + nc + 0] = v.x;
    Ls[kr * 65 + nc + 1] = v.y;
    Ls[kr * 65 + nc + 2] = v.z;
    Ls[kr * 65 + nc + 3] = v.w;
  }
  __syncthreads();
#pragma unroll
  for (int u = 0; u < 2; ++u) {
    int flat = t + 256 * u;
    int nr = flat >> 3, kc = (flat & 7) * 8;
    bf16x8 o;
#pragma unroll
    for (int j = 0; j < 8; ++j) o[j] = (__bf16)Ls[(kc + j) * 65 + nr];
    *(uint4*)&dst[(size_t)(n0 + nr) * Kdim + k0 + kc] = __builtin_bit_cast(uint4, o);
  }
}

// ---------------------------------------------------------------------------
// bf16 MFMA GEMM, 128x128 tile, BK=64, 256 threads (4 waves 2x2), 16x16x32 mfma.
// MODE 2 uses split-K: blockIdx.z = h*S + s, each split s writes its own fp32
// partial buffer F0 + s*H*L*L (store on first chunk, += on later chunks).
// ---------------------------------------------------------------------------
template <int MODE>
__global__ __launch_bounds__(256) void mm_k(
    const __bf16* __restrict__ A, const __bf16* __restrict__ B,
    const float* __restrict__ bias, const float* __restrict__ tie,
    __bf16* __restrict__ O0, __bf16* __restrict__ O1, __bf16* __restrict__ O2,
    float* __restrict__ F0,
    int K, int c0, int Rc, int KT, int firstChunk, int S) {
  __shared__ __bf16 As[128 * 72];
  __shared__ __bf16 Bs[128 * 72];
  const int t = threadIdx.x;
  const int lane = t & 63, w = t >> 6;
  const int wm = w >> 1, wn = w & 1;
  const int n0 = blockIdx.x * 128;
  const int m0 = blockIdx.y * 128;
  int h = 0, s = 0, kOff = 0;
  if (MODE == 2) { h = blockIdx.z / S; s = blockIdx.z % S; kOff = s * K; }
  if (MODE == 3) h = blockIdx.z;
  const int bz = blockIdx.z;

  f32x4 acc[4][4];
#pragma unroll
  for (int i = 0; i < 4; ++i)
#pragma unroll
    for (int j = 0; j < 4; ++j) acc[i][j] = (f32x4){0.f, 0.f, 0.f, 0.f};

  for (int k0 = 0; k0 < K; k0 += 64) {
#pragma unroll
    for (int u = 0; u < 4; ++u) {
      int flat = t + 256 * u;
      int row = flat >> 3;
      int c8 = (flat & 7) << 3;
      const __bf16* ap;
      int p = m0 + row;
      if (MODE == 0) ap = A + ((size_t)((p & 127) * L_ + c0 + (p >> 7))) * 128 + k0 + c8;
      else if (MODE == 1) ap = A + ((size_t)(c0 * L_ + p)) * 128 + k0 + c8;
      else if (MODE == 2) ap = A + ((size_t)(h * L_ + p)) * KT + kOff + k0 + c8;
      else if (MODE == 3) ap = A + ((size_t)(h * L_ + p)) * L_ + k0 + c8;
      else if (MODE == 4) ap = A + (size_t)p * INNER_ + k0 + c8;
      else if (MODE == 5) {
        int rrel = p / L_, l = p - rrel * L_;
        ap = A + (((size_t)((k0 >> 6) * L_ + l)) * Rc + rrel) * 64 + c8;
      } else ap = A + (size_t)p * 128 + k0 + c8;
      uint4 av = *(const uint4*)ap;
      if (MODE == 2) {
        float tw = tie[((size_t)p * H_ + h) * R_ + c0 + ((kOff + k0 + c8) >> 6)];
        bf16x8 bv = __builtin_bit_cast(bf16x8, av);
#pragma unroll
        for (int j = 0; j < 8; ++j) bv[j] = (__bf16)((float)bv[j] * tw);
        av = __builtin_bit_cast(uint4, bv);
      }
      *(uint4*)&As[row * 72 + c8] = av;
      const __bf16* bp;
      int n = n0 + row;
      if (MODE == 0 || MODE == 1) bp = B + (size_t)n * 128 + k0 + c8;
      else if (MODE == 2) bp = B + ((size_t)(h * L_ + n)) * KT + kOff + k0 + c8;
      else if (MODE == 3) bp = B + ((size_t)(h * Rc * 64 + n)) * L_ + k0 + c8;
      else if (MODE == 4 || MODE == 5) bp = B + (size_t)n * INNER_ + k0 + c8;
      else bp = B + ((size_t)((c0 + bz) * L_ + n)) * 128 + k0 + c8;
      *(uint4*)&Bs[row * 72 + c8] = *(const uint4*)bp;
    }
    __syncthreads();
    {
      int lc = lane & 15, q8 = (lane >> 4) << 3;
#pragma unroll
      for (int kt = 0; kt < 2; ++kt) {
        bf16x8 af[4], bfr[4];
#pragma unroll
        for (int i = 0; i < 4; ++i) {
          af[i] = *(const bf16x8*)&As[(wm * 64 + i * 16 + lc) * 72 + kt * 32 + q8];
          bfr[i] = *(const bf16x8*)&Bs[(wn * 64 + i * 16 + lc) * 72 + kt * 32 + q8];
        }
#pragma unroll
        for (int i = 0; i < 4; ++i)
#pragma unroll
          for (int j = 0; j < 4; ++j)
            acc[i][j] = __builtin_amdgcn_mfma_f32_16x16x32_bf16(af[i], bfr[j], acc[i][j], 0, 0, 0);
      }
    }
    __syncthreads();
  }

  int lce = lane & 15, lr4 = (lane >> 4) << 2;
#pragma unroll
  for (int i = 0; i < 4; ++i) {
#pragma unroll
    for (int j = 0; j < 4; ++j) {
#pragma unroll
      for (int g = 0; g < 4; ++g) {
        int pm = m0 + wm * 64 + i * 16 + lr4 + g;
        int pn = n0 + wn * 64 + j * 16 + lce;
        float v = acc[i][j][g];
        if (MODE == 0) {
          __bf16* buf;
          int nn = pn;
          if (nn < 512) buf = O0;
          else if (nn < 1024) { buf = O1; nn -= 512; }
          else { buf = O2; nn -= 1024; }
          int hh = nn >> 6, dh = nn & 63;
          int lrel = pm >> 7, rr = pm & 127;
          buf[(((size_t)(lrel * H_ + hh)) * R_ + rr) * 64 + dh] = (__bf16)v;
        } else if (MODE == 1) {
          __bf16* buf;
          int nn = pn;
          if (nn < 512) buf = O0;
          else { buf = O1; nn -= 512; }
          int hh = nn >> 6, dh = nn & 63;
          int rrel = pm / L_, l = pm - rrel * L_;
          buf[(((size_t)(hh * L_ + l)) * Rc + rrel) * 64 + dh] = (__bf16)v;
        } else if (MODE == 2) {
          float* ptr = F0 + ((size_t)(s * H_ + h)) * (L_ * L_) + (size_t)pm * L_ + pn;
          float val = 0.125f * v;
          if (firstChunk) *ptr = val;
          else *ptr += val;
        } else if (MODE == 3) {
          O0[((size_t)(h * L_ + pm)) * ((size_t)Rc * 64) + pn] = (__bf16)v;
        } else if (MODE == 4) {
          int lrel = pm >> 7, rr = pm & 127;
          F0[((size_t)(rr * L_ + c0 + lrel)) * 128 + pn] = 0.5f * (v + bias[pn]);
        } else if (MODE == 5) {
          int rrel = pm / L_, l = pm - rrel * L_;
          float* ptr = F0 + ((size_t)((c0 + rrel) * L_ + l)) * 128 + pn;
          *ptr += 0.5f * (v + bias[pn]);
        } else {
          O0[(((size_t)((pm >> 6) * Rc + bz)) * 64 + (pm & 63)) * (size_t)L_ + pn] = (__bf16)v;
        }
      }
    }
  }
}

// ---------------------------------------------------------------------------
// fp32 NN GEMM + bias (ks / qs projections), 64x64 tile, K=128
// ---------------------------------------------------------------------------
__global__ __launch_bounds__(256) void gemm6_k(const float* __restrict__ A,
                                               const float* __restrict__ B,
                                               const float* __restrict__ bias,
                                               float* __restrict__ C) {
  __shared__ float As[64][68];
  __shared__ float Bs[64][68];
  const int t = threadIdx.x;
  const int tx = t & 15, ty = t >> 4;
  const int n0 = blockIdx.x * 64;
  const int m0 = blockIdx.y * 64;
  float acc[4][4] = {};
  for (int k0 = 0; k0 < 128; k0 += 64) {
#pragma unroll
    for (int u = 0; u < 4; ++u) {
      int f = t + 256 * u;
      int mr = f >> 4, kq = (f & 15) << 2;
      float4 v = *(const float4*)(A + ((size_t)(m0 + mr)) * 128 + k0 + kq);
      As[kq + 0][mr] = v.x; As[kq + 1][mr] = v.y;
      As[kq + 2][mr] = v.z; As[kq + 3][mr] = v.w;
      *(float4*)&Bs[mr][kq] = *(const float4*)(B + (size_t)(k0 + mr) * 128 + n0 + kq);
    }
    __syncthreads();
#pragma unroll
    for (int kk = 0; kk < 64; ++kk) {
      float4 a = *(const float4*)&As[kk][ty << 2];
      float4 b = *(const float4*)&Bs[kk][tx << 2];
      acc[0][0] = fmaf(a.x, b.x, acc[0][0]); acc[0][1] = fmaf(a.x, b.y, acc[0][1]);
      acc[0][2] = fmaf(a.x, b.z, acc[0][2]); acc[0][3] = fmaf(a.x, b.w, acc[0][3]);
      acc[1][0] = fmaf(a.y, b.x, acc[1][0]); acc[1][1] = fmaf(a.y, b.y, acc[1][1]);
      acc[1][2] = fmaf(a.y, b.z, acc[1][2]); acc[1][3] = fmaf(a.y, b.w, acc[1][3]);
      acc[2][0] = fmaf(a.z, b.x, acc[2][0]); acc[2][1] = fmaf(a.z, b.y, acc[2][1]);
      acc[2][2] = fmaf(a.z, b.z, acc[2][2]); acc[2][3] = fmaf(a.z, b.w, acc[2][3]);
      acc[3][0] = fmaf(a.w, b.x, acc[3][0]); acc[3][1] = fmaf(a.w, b.y, acc[3][1]);
      acc[3][2] = fmaf(a.w, b.z, acc[3][2]); acc[3][3] = fmaf(a.w, b.w, acc[3][3]);
    }
    __syncthreads();
  }
#pragma unroll
  for (int i = 0; i < 4; ++i) {
    int p = m0 + (ty << 2) + i;
    int n = n0 + (tx << 2);
    float4 r;
    r.x = acc[i][0]; r.y = acc[i][1]; r.z = acc[i][2]; r.w = acc[i][3];
    float4 bb = *(const float4*)&bias[n];
    r.x += bb.x; r.y += bb.y; r.z += bb.z; r.w += bb.w;
    *(float4*)(C + (size_t)p * 128 + n) = r;
  }
}

// ---------------------------------------------------------------------------
// tie softmax
// ---------------------------------------------------------------------------
__global__ __launch_bounds__(128) void tie_kernel(const float* __restrict__ qs,
                                                  const float* __restrict__ ks,
                                                  float* __restrict__ wtie) {
  int bid = blockIdx.x;
  int l = bid >> 3, h = bid & 7;
  int r = threadIdx.x;
  int wid = r >> 6;
  const float* qp = qs + (size_t)l * 128 + h * 16;
  const float* kp = ks + ((size_t)r * L_ + l) * 128 + h * 16;
  float s = 0.f;
#pragma unroll
  for (int i = 0; i < 16; ++i) s += qp[i] * kp[i];
  s *= 0.25f;
  __shared__ float sm[2], ss[2];
  float wm = wred_max(s);
  if ((r & 63) == 0) sm[wid] = wm;
  __syncthreads();
  float mx = fmaxf(sm[0], sm[1]);
  float e = __expf(s - mx);
  float wsum = wred_sum(e);
  if ((r & 63) == 0) ss[wid] = wsum;
  __syncthreads();
  float tot = ss[0] + ss[1];
  wtie[((size_t)l * H_ + h) * R_ + r] = e / tot;
}

// ---------------------------------------------------------------------------
// pair LN + Wpair -> pair-bias buffer pb[h][i][j]
// ---------------------------------------------------------------------------
__global__ __launch_bounds__(256) void lnpb_kernel(const float* __restrict__ pair,
                                                   const float* __restrict__ g,
                                                   const float* __restrict__ b,
                                                   const float* __restrict__ wp,
                                                   float* __restrict__ pb) {
  int wid = threadIdx.x >> 6, lane = threadIdx.x & 63;
  int pid = blockIdx.x * 4 + wid;
  const float* xp = pair + (size_t)pid * 128 + lane * 2;
  float2 x = *(const float2*)xp;
  float mu = wred_sum(x.x + x.y) * (1.0f / 128.0f);
  float d0 = x.x - mu, d1 = x.y - mu;
  float var = wred_sum(d0 * d0 + d1 * d1) * (1.0f / 128.0f);
  float rs = 1.0f / sqrtf(var + 1e-5f);
  float y0 = d0 * rs * g[lane * 2] + b[lane * 2];
  float y1 = d1 * rs * g[lane * 2 + 1] + b[lane * 2 + 1];
  float ph[8];
#pragma unroll
  for (int hh = 0; hh < 8; ++hh)
    ph[hh] = y0 * wp[lane * 16 + hh] + y1 * wp[lane * 16 + 8 + hh];
#pragma unroll
  for (int hh = 0; hh < 8; ++hh) ph[hh] = wred_sum(ph[hh]);
  if (lane < 8) pb[(size_t)lane * (L_ * L_) + pid] = ph[lane];
}

// ---------------------------------------------------------------------------
// softmax over last dim of (pb + sum of S split-K partials) -> attn bf16
// ---------------------------------------------------------------------------
__global__ __launch_bounds__(128) void sm_kernel(const float* __restrict__ pb,
                                                 const float* __restrict__ dp,
                                                 int S, __bf16* __restrict__ ab) {
  size_t row = blockIdx.x;
  int t = threadIdx.x;
  int wid = t >> 6;
  const float* p0 = pb + row * L_;
  float x0 = p0[t], x1 = p0[t + 128], x2 = p0[t + 256];
  const size_t HLL = (size_t)H_ * L_ * L_;
  for (int s = 0; s < S; ++s) {
    const float* ps = dp + s * HLL + row * L_;
    x0 += ps[t]; x1 += ps[t + 128]; x2 += ps[t + 256];
  }
  __shared__ float sm[2], ss[2];
  float m = wred_max(fmaxf(x0, fmaxf(x1, x2)));
  if ((t & 63) == 0) sm[wid] = m;
  __syncthreads();
  m = fmaxf(sm[0], sm[1]);
  float e0 = __expf(x0 - m), e1 = __expf(x1 - m), e2 = __expf(x2 - m);
  float s2 = wred_sum(e0 + e1 + e2);
  if ((t & 63) == 0) ss[wid] = s2;
  __syncthreads();
  float inv = 1.0f / (ss[0] + ss[1]);
  __bf16* op = ab + row * L_;
  op[t] = (__bf16)(e0 * inv);
  op[t + 128] = (__bf16)(e1 * inv);
  op[t + 256] = (__bf16)(e2 * inv);
}

// ---------------------------------------------------------------------------
// column attention, MFMA version (unchanged from round 3)
// ---------------------------------------------------------------------------
__global__ __launch_bounds__(256) void attw_kernel(const __bf16* __restrict__ qb,
                                                   const __bf16* __restrict__ kb,
                                                   const __bf16* __restrict__ vb,
                                                   __bf16* __restrict__ ob) {
  __shared__ __bf16 smem[27136];
  __bf16* Qs = smem;
  __bf16* Ks = smem + 9216;
  __bf16* Vt = smem + 18432;
  __bf16* Ps = smem;
  int bid = blockIdx.x;
  int lrel = bid >> 3, h = bid & 7;
  size_t base = (size_t)(lrel * H_ + h) * (128 * 64);
  int t = threadIdx.x;
#pragma unroll
  for (int u = 0; u < 4; ++u) {
    int flat = t + 256 * u;
    int row = flat >> 3, c8 = (flat & 7) << 3;
    *(uint4*)&Qs[row * 72 + c8] = *(const uint4*)&qb[base + (size_t)row * 64 + c8];
    *(uint4*)&Ks[row * 72 + c8] = *(const uint4*)&kb[base + (size_t)row * 64 + c8];
  }
#pragma unroll
  for (int u = 0; u < 4; ++u) {
    int idx = t + 256 * u;
    int r = idx & 127, c8 = (idx >> 7) << 3;
    bf16x8 v = *(const bf16x8*)&vb[base + (size_t)r * 64 + c8];
#pragma unroll
    for (int j = 0; j < 8; ++j) Vt[(c8 + j) * 136 + r] = v[j];
  }
  __syncthreads();

  const int lane = t & 63, w = t >> 6;
  const int lc = lane & 15, q8 = (lane >> 4) << 3;

  f32x4 s[2][8];
#pragma unroll
  for (int i = 0; i < 2; ++i)
#pragma unroll
    for (int n = 0; n < 8; ++n) s[i][n] = (f32x4){0.f, 0.f, 0.f, 0.f};
#pragma unroll
  for (int kt = 0; kt < 2; ++kt) {
    bf16x8 a[2];
#pragma unroll
    for (int i = 0; i < 2; ++i)
      a[i] = *(const bf16x8*)&Qs[(w * 32 + i * 16 + lc) * 72 + kt * 32 + q8];
#pragma unroll
    for (int n = 0; n < 8; ++n) {
      bf16x8 b = *(const bf16x8*)&Ks[(n * 16 + lc) * 72 + kt * 32 + q8];
#pragma unroll
      for (int i = 0; i < 2; ++i)
        s[i][n] = __builtin_amdgcn_mfma_f32_16x16x32_bf16(a[i], b, s[i][n], 0, 0, 0);
    }
  }

  float linv[2][4];
#pragma unroll
  for (int i = 0; i < 2; ++i) {
#pragma unroll
    for (int g = 0; g < 4; ++g) {
      float mx = -1e30f;
#pragma unroll
      for (int n = 0; n < 8; ++n) mx = fmaxf(mx, s[i][n][g]);
      mx = fmaxf(mx, __shfl_xor(mx, 1, 64));
      mx = fmaxf(mx, __shfl_xor(mx, 2, 64));
      mx = fmaxf(mx, __shfl_xor(mx, 4, 64));
      mx = fmaxf(mx, __shfl_xor(mx, 8, 64));
      float sum = 0.f;
#pragma unroll
      for (int n = 0; n < 8; ++n) {
        float e = __expf(0.125f * (s[i][n][g] - mx));
        s[i][n][g] = e;
        sum += e;
      }
      sum += __shfl_xor(sum, 1, 64);
      sum += __shfl_xor(sum, 2, 64);
      sum += __shfl_xor(sum, 4, 64);
      sum += __shfl_xor(sum, 8, 64);
      linv[i][g] = 1.0f / sum;
    }
  }
  __syncthreads();

#pragma unroll
  for (int i = 0; i < 2; ++i)
#pragma unroll
    for (int n = 0; n < 8; ++n)
#pragma unroll
      for (int g = 0; g < 4; ++g) {
        int row = w * 32 + i * 16 + ((lane >> 4) << 2) + g;
        int col = n * 16 + lc;
        Ps[row * 140 + col] = (__bf16)s[i][n][g];
      }
  __syncthreads();

  f32x4 o[2][4];
#pragma unroll
  for (int i = 0; i < 2; ++i)
#pragma unroll
    for (int n = 0; n < 4; ++n) o[i][n] = (f32x4){0.f, 0.f, 0.f, 0.f};
#pragma unroll
  for (int kt = 0; kt < 4; ++kt) {
    bf16x8 a[2];
#pragma unroll
    for (int i = 0; i < 2; ++i)
      a[i] = *(const bf16x8*)&Ps[(w * 32 + i * 16 + lc) * 140 + kt * 32 + q8];
#pragma unroll
    for (int n = 0; n < 4; ++n) {
      bf16x8 b = *(const bf16x8*)&Vt[(n * 16 + lc) * 136 + kt * 32 + q8];
#pragma unroll
      for (int i = 0; i < 2; ++i)
        o[i][n] = __builtin_amdgcn_mfma_f32_16x16x32_bf16(a[i], b, o[i][n], 0, 0, 0);
    }
  }

#pragma unroll
  for (int i = 0; i < 2; ++i)
#pragma unroll
    for (int n = 0; n < 4; ++n)
#pragma unroll
      for (int g = 0; g < 4; ++g) {
        int r = w * 32 + i * 16 + ((lane >> 4) << 2) + g;
        int dh = n * 16 + lc;
        ob[((size_t)(lrel * R_ + r)) * INNER_ + h * 64 + dh] =
            (__bf16)(o[i][n][g] * linv[i][g]);
      }
}

// ---------------------------------------------------------------------------
extern "C" void kernel_launch(void* const* d_in, const int* in_sizes, int n_in,
                              void* d_out, int out_size, void* d_ws,
                              size_t ws_size, hipStream_t stream) {
  (void)in_sizes; (void)n_in; (void)out_size;
  const float* m = (const float*)d_in[0];
  const float* pair = (const float*)d_in[1];
  const float* Wq_w = (const float*)d_in[2];
  const float* Wkv_w = (const float*)d_in[3];
  const float* Wo_w = (const float*)d_in[4];
  const float* bo_w = (const float*)d_in[5];
  const float* Wq_h = (const float*)d_in[6];
  const float* Wkv_h = (const float*)d_in[7];
  const float* Wo_h = (const float*)d_in[8];
  const float* bo_h = (const float*)d_in[9];
  const float* ln_g = (const float*)d_in[10];
  const float* ln_b = (const float*)d_in[11];
  const float* Wpair = (const float*)d_in[12];
  const float* Wsq = (const float*)d_in[13];
  const float* bsq = (const float*)d_in[14];
  const float* Wsk = (const float*)d_in[15];
  const float* bsk = (const float*)d_in[16];
  float* out = (float*)d_out;

  // ---- choose chunking (CH) and split count (S = 8/CH) to fit workspace ----
  const size_t fixedBase = 22478848u;  // everything before dotsP (bytes)
  int CH = 1;
  for (; CH < 8; CH *= 2) {
    size_t partials = (size_t)(8 / CH) * 4718592u;
    size_t o = 201326592u / CH;
    if (o < 25165824u) o = 25165824u;
    if (fixedBase + partials + o <= ws_size) break;
  }
  const int S = 8 / CH;
  const int Lc = L_ / CH;
  const int Rc = R_ / CH;

  unsigned char* base = (unsigned char*)d_ws;
  __bf16* m_bf = (__bf16*)base;       base += 12582912;
  __bf16* WTw = (__bf16*)base;        base += 393216;
  __bf16* WThqk = (__bf16*)base;      base += 262144;
  __bf16* WTvh = (__bf16*)base;       base += 131072;
  __bf16* WoTw = (__bf16*)base;       base += 131072;
  __bf16* WoTh = (__bf16*)base;       base += 131072;
  float* wtie = (float*)base;         base += 1572864;
  float* pb = (float*)base;           base += 4718592;
  __bf16* attnb = (__bf16*)base;      base += 2359296;
  float* qsb = (float*)base;          base += 196608;
  float* dotsP = (float*)base;        base += (size_t)S * 4718592u;
  unsigned char* ovl = base;
  float* ksb = (float*)ovl;

  const size_t BUF = 25165824u / CH;
  __bf16* qb = (__bf16*)ovl;
  __bf16* kb = qb + BUF;
  __bf16* vb = kb + BUF;
  __bf16* ob = vb + BUF;

  cvt_kernel<<<3072, 256, 0, stream>>>(m, m_bf, 786432);
  wt_kernel<<<dim3(8, 2), 256, 0, stream>>>(Wq_w, WTw, 128, 512, 0);
  wt_kernel<<<dim3(16, 2), 256, 0, stream>>>(Wkv_w, WTw + 512 * 128, 128, 1024, 0);
  wt_kernel<<<dim3(8, 2), 256, 0, stream>>>(Wq_h, WThqk, 128, 512, 0);
  wt_kernel<<<dim3(8, 2), 256, 0, stream>>>(Wkv_h, WThqk + 512 * 128, 128, 1024, 0);
  wt_kernel<<<dim3(8, 2), 256, 0, stream>>>(Wkv_h, WTvh, 128, 1024, 512);
  wt_kernel<<<dim3(2, 8), 256, 0, stream>>>(Wo_w, WoTw, 512, 128, 0);
  wt_kernel<<<dim3(2, 8), 256, 0, stream>>>(Wo_h, WoTh, 512, 128, 0);

  gemm6_k<<<dim3(2, 768), 256, 0, stream>>>(m, Wsk, bsk, ksb);
  gemm6_k<<<dim3(2, 6), 256, 0, stream>>>(m, Wsq, bsq, qsb);
  tie_kernel<<<L_ * H_, 128, 0, stream>>>(qsb, ksb, wtie);
  lnpb_kernel<<<(L_ * L_) / 4, 256, 0, stream>>>(pair, ln_g, ln_b, Wpair, pb);

  for (int c = 0; c < CH; ++c) {
    int l0 = c * Lc;
    mm_k<0><<<dim3(12, Lc), 256, 0, stream>>>(m_bf, WTw, nullptr, nullptr, qb, kb, vb,
                                              nullptr, 128, l0, Rc, 0, 0, 1);
    attw_kernel<<<Lc * H_, 256, 0, stream>>>(qb, kb, vb, ob);
    mm_k<4><<<dim3(1, Lc), 256, 0, stream>>>(ob, WoTw, bo_w, nullptr, nullptr, nullptr,
                                             nullptr, out, 512, l0, Rc, 0, 0, 1);
  }

  for (int c = 0; c < CH; ++c) {
    int r0 = c * Rc;
    mm_k<1><<<dim3(8, Rc * 3), 256, 0, stream>>>(m_bf, WThqk, nullptr, nullptr, qb, kb,
                                                 nullptr, nullptr, 128, r0, Rc, 0, 0, 1);
    // split-K dots: per chunk, K = Rc*64 split into S pieces of (Rc*64)/S
    mm_k<2><<<dim3(3, 3, H_ * S), 256, 0, stream>>>(qb, kb, nullptr, wtie, nullptr,
                                                    nullptr, nullptr, dotsP,
                                                    (Rc * 64) / S, r0, Rc, Rc * 64,
                                                    (c == 0) ? 1 : 0, S);
  }
  sm_kernel<<<H_ * L_, 128, 0, stream>>>(pb, dotsP, S, attnb);

  for (int c = 0; c < CH; ++c) {
    int r0 = c * Rc;
    mm_k<6><<<dim3(3, 4, Rc), 256, 0, stream>>>(WTvh, m_bf, nullptr, nullptr, vb, nullptr,
                                                nullptr, nullptr, 128, r0, Rc, 0, 0, 1);
    mm_k<3><<<dim3(Rc / 2, 3, 8), 256, 0, stream>>>(attnb, vb, nullptr, nullptr, ob, nullptr,
                                                    nullptr, nullptr, 384, r0, Rc, 0, 0, 1);
    mm_k<5><<<dim3(1, Rc * 3), 256, 0, stream>>>(ob, WoTh, bo_h, nullptr, nullptr, nullptr,
                                                 nullptr, out, 512, r0, Rc, 0, 0, 1);
  }
}

// Round 5
// 541.689 us; speedup vs baseline: 4.7160x; 1.1344x over previous
//
#include <hip/hip_runtime.h>
#include <math.h>

#define L_ 384
#define R_ 128
#define D_ 128
#define H_ 8
#define DH_ 64
#define INNER_ 512

typedef __bf16 bf16x8 __attribute__((ext_vector_type(8)));
typedef __bf16 bf16x4 __attribute__((ext_vector_type(4)));
typedef float f32x4 __attribute__((ext_vector_type(4)));

__device__ __forceinline__ float wred_sum(float v) {
#pragma unroll
  for (int o = 32; o > 0; o >>= 1) v += __shfl_xor(v, o, 64);
  return v;
}
__device__ __forceinline__ float wred_max(float v) {
#pragma unroll
  for (int o = 32; o > 0; o >>= 1) v = fmaxf(v, __shfl_xor(v, o, 64));
  return v;
}

// ---------------------------------------------------------------------------
// fp32 -> bf16 elementwise (8 per thread)
// ---------------------------------------------------------------------------
__global__ __launch_bounds__(256) void cvt_kernel(const float* __restrict__ in,
                                                  __bf16* __restrict__ out, int n8) {
  int i = blockIdx.x * 256 + threadIdx.x;
  if (i >= n8) return;
  float4 a = *(const float4*)(in + (size_t)i * 8);
  float4 b = *(const float4*)(in + (size_t)i * 8 + 4);
  bf16x8 o;
  o[0] = (__bf16)a.x; o[1] = (__bf16)a.y; o[2] = (__bf16)a.z; o[3] = (__bf16)a.w;
  o[4] = (__bf16)b.x; o[5] = (__bf16)b.y; o[6] = (__bf16)b.z; o[7] = (__bf16)b.w;
  *(uint4*)(out + (size_t)i * 8) = __builtin_bit_cast(uint4, o);
}

// ---------------------------------------------------------------------------
// weight transpose+convert: src fp32 [Kdim][Nstride] (cols n_off..) -> dst bf16 [N][Kdim]
// ---------------------------------------------------------------------------
__global__ __launch_bounds__(256) void wt_kernel(const float* __restrict__ src,
                                                 __bf16* __restrict__ dst, int Kdim,
                                                 int Nstride, int n_off) {
  __shared__ float Ls[64 * 65];
  int n0 = blockIdx.x * 64, k0 = blockIdx.y * 64;
  int t = threadIdx.x;
#pragma unroll
  for (int u = 0; u < 4; ++u) {
    int flat = t + 256 * u;
    int kr = flat >> 4, nc = (flat & 15) * 4;
    float4 v = *(const float4*)&src[(size_t)(k0 + kr) * Nstride + n_off + n0 + nc];
    Ls[kr * 65 + nc + 0] = v.x;
    Ls[kr * 65 + nc + 1] = v.y;
    Ls[kr * 65 + nc + 2] = v.z;
    Ls[kr * 65 + nc + 3] = v.w;
  }
  __syncthreads();
#pragma unroll
  for (int u = 0; u < 2; ++u) {
    int flat = t + 256 * u;
    int nr = flat >> 3, kc = (flat & 7) * 8;
    bf16x8 o;
#pragma unroll
    for (int j = 0; j < 8; ++j) o[j] = (__bf16)Ls[(kc + j) * 65 + nr];
    *(uint4*)&dst[(size_t)(n0 + nr) * Kdim + k0 + kc] = __builtin_bit_cast(uint4, o);
  }
}

// ---------------------------------------------------------------------------
// bf16 MFMA GEMM, 128x128 tile, BK=64, 256 threads (4 waves 2x2), 16x16x32 mfma.
// MODE 2 split-K; MODE 7: plain NT projection, C = bf16(acc + bias) at [p][128].
// ---------------------------------------------------------------------------
template <int MODE>
__global__ __launch_bounds__(256) void mm_k(
    const __bf16* __restrict__ A, const __bf16* __restrict__ B,
    const float* __restrict__ bias, const float* __restrict__ tie,
    __bf16* __restrict__ O0, __bf16* __restrict__ O1, __bf16* __restrict__ O2,
    float* __restrict__ F0,
    int K, int c0, int Rc, int KT, int firstChunk, int S) {
  __shared__ __bf16 As[128 * 72];
  __shared__ __bf16 Bs[128 * 72];
  const int t = threadIdx.x;
  const int lane = t & 63, w = t >> 6;
  const int wm = w >> 1, wn = w & 1;
  const int n0 = blockIdx.x * 128;
  const int m0 = blockIdx.y * 128;
  int h = 0, s = 0, kOff = 0;
  if (MODE == 2) { h = blockIdx.z / S; s = blockIdx.z % S; kOff = s * K; }
  if (MODE == 3) h = blockIdx.z;
  const int bz = blockIdx.z;

  f32x4 acc[4][4];
#pragma unroll
  for (int i = 0; i < 4; ++i)
#pragma unroll
    for (int j = 0; j < 4; ++j) acc[i][j] = (f32x4){0.f, 0.f, 0.f, 0.f};

  for (int k0 = 0; k0 < K; k0 += 64) {
#pragma unroll
    for (int u = 0; u < 4; ++u) {
      int flat = t + 256 * u;
      int row = flat >> 3;
      int c8 = (flat & 7) << 3;
      const __bf16* ap;
      int p = m0 + row;
      if (MODE == 0) ap = A + ((size_t)((p & 127) * L_ + c0 + (p >> 7))) * 128 + k0 + c8;
      else if (MODE == 1) ap = A + ((size_t)(c0 * L_ + p)) * 128 + k0 + c8;
      else if (MODE == 2) ap = A + ((size_t)(h * L_ + p)) * KT + kOff + k0 + c8;
      else if (MODE == 3) ap = A + ((size_t)(h * L_ + p)) * L_ + k0 + c8;
      else if (MODE == 4) ap = A + (size_t)p * INNER_ + k0 + c8;
      else if (MODE == 5) {
        int rrel = p / L_, l = p - rrel * L_;
        ap = A + (((size_t)((k0 >> 6) * L_ + l)) * Rc + rrel) * 64 + c8;
      } else ap = A + (size_t)p * 128 + k0 + c8;
      uint4 av = *(const uint4*)ap;
      if (MODE == 2) {
        float tw = tie[((size_t)p * H_ + h) * R_ + c0 + ((kOff + k0 + c8) >> 6)];
        bf16x8 bv = __builtin_bit_cast(bf16x8, av);
#pragma unroll
        for (int j = 0; j < 8; ++j) bv[j] = (__bf16)((float)bv[j] * tw);
        av = __builtin_bit_cast(uint4, bv);
      }
      *(uint4*)&As[row * 72 + c8] = av;
      const __bf16* bp;
      int n = n0 + row;
      if (MODE == 0 || MODE == 1 || MODE == 7) bp = B + (size_t)n * 128 + k0 + c8;
      else if (MODE == 2) bp = B + ((size_t)(h * L_ + n)) * KT + kOff + k0 + c8;
      else if (MODE == 3) bp = B + ((size_t)(h * Rc * 64 + n)) * L_ + k0 + c8;
      else if (MODE == 4 || MODE == 5) bp = B + (size_t)n * INNER_ + k0 + c8;
      else bp = B + ((size_t)((c0 + bz) * L_ + n)) * 128 + k0 + c8;
      *(uint4*)&Bs[row * 72 + c8] = *(const uint4*)bp;
    }
    __syncthreads();
    {
      int lc = lane & 15, q8 = (lane >> 4) << 3;
#pragma unroll
      for (int kt = 0; kt < 2; ++kt) {
        bf16x8 af[4], bfr[4];
#pragma unroll
        for (int i = 0; i < 4; ++i) {
          af[i] = *(const bf16x8*)&As[(wm * 64 + i * 16 + lc) * 72 + kt * 32 + q8];
          bfr[i] = *(const bf16x8*)&Bs[(wn * 64 + i * 16 + lc) * 72 + kt * 32 + q8];
        }
#pragma unroll
        for (int i = 0; i < 4; ++i)
#pragma unroll
          for (int j = 0; j < 4; ++j)
            acc[i][j] = __builtin_amdgcn_mfma_f32_16x16x32_bf16(af[i], bfr[j], acc[i][j], 0, 0, 0);
      }
    }
    __syncthreads();
  }

  int lce = lane & 15, lr4 = (lane >> 4) << 2;
#pragma unroll
  for (int i = 0; i < 4; ++i) {
#pragma unroll
    for (int j = 0; j < 4; ++j) {
#pragma unroll
      for (int g = 0; g < 4; ++g) {
        int pm = m0 + wm * 64 + i * 16 + lr4 + g;
        int pn = n0 + wn * 64 + j * 16 + lce;
        float v = acc[i][j][g];
        if (MODE == 0) {
          __bf16* buf;
          int nn = pn;
          if (nn < 512) buf = O0;
          else if (nn < 1024) { buf = O1; nn -= 512; }
          else { buf = O2; nn -= 1024; }
          int hh = nn >> 6, dh = nn & 63;
          int lrel = pm >> 7, rr = pm & 127;
          buf[(((size_t)(lrel * H_ + hh)) * R_ + rr) * 64 + dh] = (__bf16)v;
        } else if (MODE == 1) {
          __bf16* buf;
          int nn = pn;
          if (nn < 512) buf = O0;
          else { buf = O1; nn -= 512; }
          int hh = nn >> 6, dh = nn & 63;
          int rrel = pm / L_, l = pm - rrel * L_;
          buf[(((size_t)(hh * L_ + l)) * Rc + rrel) * 64 + dh] = (__bf16)v;
        } else if (MODE == 2) {
          float* ptr = F0 + ((size_t)(s * H_ + h)) * (L_ * L_) + (size_t)pm * L_ + pn;
          float val = 0.125f * v;
          if (firstChunk) *ptr = val;
          else *ptr += val;
        } else if (MODE == 3) {
          O0[((size_t)(h * L_ + pm)) * ((size_t)Rc * 64) + pn] = (__bf16)v;
        } else if (MODE == 4) {
          int lrel = pm >> 7, rr = pm & 127;
          F0[((size_t)(rr * L_ + c0 + lrel)) * 128 + pn] = 0.5f * (v + bias[pn]);
        } else if (MODE == 5) {
          int rrel = pm / L_, l = pm - rrel * L_;
          float* ptr = F0 + ((size_t)((c0 + rrel) * L_ + l)) * 128 + pn;
          *ptr += 0.5f * (v + bias[pn]);
        } else if (MODE == 7) {
          O0[(size_t)pm * 128 + pn] = (__bf16)(v + bias[pn]);
        } else {
          O0[(((size_t)((pm >> 6) * Rc + bz)) * 64 + (pm & 63)) * (size_t)L_ + pn] = (__bf16)v;
        }
      }
    }
  }
}

// ---------------------------------------------------------------------------
// tie softmax (bf16 inputs)
// ---------------------------------------------------------------------------
__global__ __launch_bounds__(128) void tie_kernel(const __bf16* __restrict__ qs,
                                                  const __bf16* __restrict__ ks,
                                                  float* __restrict__ wtie) {
  int bid = blockIdx.x;
  int l = bid >> 3, h = bid & 7;
  int r = threadIdx.x;
  int wid = r >> 6;
  const __bf16* qp = qs + (size_t)l * 128 + h * 16;
  const __bf16* kp = ks + ((size_t)r * L_ + l) * 128 + h * 16;
  bf16x8 q0 = *(const bf16x8*)qp;
  bf16x8 q1 = *(const bf16x8*)(qp + 8);
  bf16x8 k0 = *(const bf16x8*)kp;
  bf16x8 k1 = *(const bf16x8*)(kp + 8);
  float s = 0.f;
#pragma unroll
  for (int i = 0; i < 8; ++i)
    s += (float)q0[i] * (float)k0[i] + (float)q1[i] * (float)k1[i];
  s *= 0.25f;
  __shared__ float sm[2], ss[2];
  float wm = wred_max(s);
  if ((r & 63) == 0) sm[wid] = wm;
  __syncthreads();
  float mx = fmaxf(sm[0], sm[1]);
  float e = __expf(s - mx);
  float wsum = wred_sum(e);
  if ((r & 63) == 0) ss[wid] = wsum;
  __syncthreads();
  float tot = ss[0] + ss[1];
  wtie[((size_t)l * H_ + h) * R_ + r] = e / tot;
}

// ---------------------------------------------------------------------------
// pair LN + Wpair -> pb[h][i][j]. One THREAD per (i,j); no cross-lane ops.
// pb[h] = rs*(x . gw[:,h] - mu*c1[h]) + c2[h], gw = g*wp, c1 = sum gw, c2 = b.wp
// ---------------------------------------------------------------------------
__global__ __launch_bounds__(256) void lnpb_kernel(const float* __restrict__ pair,
                                                   const float* __restrict__ g,
                                                   const float* __restrict__ b,
                                                   const float* __restrict__ wp,
                                                   float* __restrict__ pb) {
  __shared__ float gws[1024];
  __shared__ float c1s[8], c2s[8];
  int t = threadIdx.x;
#pragma unroll
  for (int u = 0; u < 4; ++u) {
    int idx = t * 4 + u;  // 0..1023
    int d = idx >> 3, h = idx & 7;
    gws[idx] = g[d] * wp[d * 8 + h];
  }
  __syncthreads();
  if (t < 8) {
    float s1 = 0.f, s2 = 0.f;
    for (int d = 0; d < 128; ++d) {
      s1 += gws[d * 8 + t];
      s2 += b[d] * wp[d * 8 + t];
    }
    c1s[t] = s1;
    c2s[t] = s2;
  }
  __syncthreads();
  int pid = blockIdx.x * 256 + t;
  const float4* xp = (const float4*)(pair + (size_t)pid * 128);
  float sum = 0.f, sumsq = 0.f;
  float dots[8] = {};
#pragma unroll 8
  for (int i = 0; i < 32; ++i) {
    float4 v = xp[i];
#pragma unroll
    for (int j = 0; j < 4; ++j) {
      float e = (&v.x)[j];
      sum += e;
      sumsq = fmaf(e, e, sumsq);
      const float* gr = &gws[(i * 4 + j) * 8];
#pragma unroll
      for (int hh = 0; hh < 8; ++hh) dots[hh] = fmaf(e, gr[hh], dots[hh]);
    }
  }
  float mu = sum * (1.0f / 128.0f);
  float var = sumsq * (1.0f / 128.0f) - mu * mu;
  float rs = 1.0f / sqrtf(var + 1e-5f);
#pragma unroll
  for (int hh = 0; hh < 8; ++hh)
    pb[(size_t)hh * (L_ * L_) + pid] = rs * (dots[hh] - mu * c1s[hh]) + c2s[hh];
}

// ---------------------------------------------------------------------------
// softmax over last dim of (pb + sum of S split-K partials) -> attn bf16
// ---------------------------------------------------------------------------
__global__ __launch_bounds__(128) void sm_kernel(const float* __restrict__ pb,
                                                 const float* __restrict__ dp,
                                                 int S, __bf16* __restrict__ ab) {
  size_t row = blockIdx.x;
  int t = threadIdx.x;
  int wid = t >> 6;
  const float* p0 = pb + row * L_;
  float x0 = p0[t], x1 = p0[t + 128], x2 = p0[t + 256];
  const size_t HLL = (size_t)H_ * L_ * L_;
  for (int s = 0; s < S; ++s) {
    const float* ps = dp + s * HLL + row * L_;
    x0 += ps[t]; x1 += ps[t + 128]; x2 += ps[t + 256];
  }
  __shared__ float sm[2], ss[2];
  float m = wred_max(fmaxf(x0, fmaxf(x1, x2)));
  if ((t & 63) == 0) sm[wid] = m;
  __syncthreads();
  m = fmaxf(sm[0], sm[1]);
  float e0 = __expf(x0 - m), e1 = __expf(x1 - m), e2 = __expf(x2 - m);
  float s2 = wred_sum(e0 + e1 + e2);
  if ((t & 63) == 0) ss[wid] = s2;
  __syncthreads();
  float inv = 1.0f / (ss[0] + ss[1]);
  __bf16* op = ab + row * L_;
  op[t] = (__bf16)(e0 * inv);
  op[t + 128] = (__bf16)(e1 * inv);
  op[t + 256] = (__bf16)(e2 * inv);
}

// ---------------------------------------------------------------------------
// column attention, MFMA version
// ---------------------------------------------------------------------------
__global__ __launch_bounds__(256) void attw_kernel(const __bf16* __restrict__ qb,
                                                   const __bf16* __restrict__ kb,
                                                   const __bf16* __restrict__ vb,
                                                   __bf16* __restrict__ ob) {
  __shared__ __bf16 smem[27136];
  __bf16* Qs = smem;
  __bf16* Ks = smem + 9216;
  __bf16* Vt = smem + 18432;
  __bf16* Ps = smem;
  int bid = blockIdx.x;
  int lrel = bid >> 3, h = bid & 7;
  size_t base = (size_t)(lrel * H_ + h) * (128 * 64);
  int t = threadIdx.x;
#pragma unroll
  for (int u = 0; u < 4; ++u) {
    int flat = t + 256 * u;
    int row = flat >> 3, c8 = (flat & 7) << 3;
    *(uint4*)&Qs[row * 72 + c8] = *(const uint4*)&qb[base + (size_t)row * 64 + c8];
    *(uint4*)&Ks[row * 72 + c8] = *(const uint4*)&kb[base + (size_t)row * 64 + c8];
  }
#pragma unroll
  for (int u = 0; u < 4; ++u) {
    int idx = t + 256 * u;
    int r = idx & 127, c8 = (idx >> 7) << 3;
    bf16x8 v = *(const bf16x8*)&vb[base + (size_t)r * 64 + c8];
#pragma unroll
    for (int j = 0; j < 8; ++j) Vt[(c8 + j) * 136 + r] = v[j];
  }
  __syncthreads();

  const int lane = t & 63, w = t >> 6;
  const int lc = lane & 15, q8 = (lane >> 4) << 3;

  f32x4 s[2][8];
#pragma unroll
  for (int i = 0; i < 2; ++i)
#pragma unroll
    for (int n = 0; n < 8; ++n) s[i][n] = (f32x4){0.f, 0.f, 0.f, 0.f};
#pragma unroll
  for (int kt = 0; kt < 2; ++kt) {
    bf16x8 a[2];
#pragma unroll
    for (int i = 0; i < 2; ++i)
      a[i] = *(const bf16x8*)&Qs[(w * 32 + i * 16 + lc) * 72 + kt * 32 + q8];
#pragma unroll
    for (int n = 0; n < 8; ++n) {
      bf16x8 b = *(const bf16x8*)&Ks[(n * 16 + lc) * 72 + kt * 32 + q8];
#pragma unroll
      for (int i = 0; i < 2; ++i)
        s[i][n] = __builtin_amdgcn_mfma_f32_16x16x32_bf16(a[i], b, s[i][n], 0, 0, 0);
    }
  }

  float linv[2][4];
#pragma unroll
  for (int i = 0; i < 2; ++i) {
#pragma unroll
    for (int g = 0; g < 4; ++g) {
      float mx = -1e30f;
#pragma unroll
      for (int n = 0; n < 8; ++n) mx = fmaxf(mx, s[i][n][g]);
      mx = fmaxf(mx, __shfl_xor(mx, 1, 64));
      mx = fmaxf(mx, __shfl_xor(mx, 2, 64));
      mx = fmaxf(mx, __shfl_xor(mx, 4, 64));
      mx = fmaxf(mx, __shfl_xor(mx, 8, 64));
      float sum = 0.f;
#pragma unroll
      for (int n = 0; n < 8; ++n) {
        float e = __expf(0.125f * (s[i][n][g] - mx));
        s[i][n][g] = e;
        sum += e;
      }
      sum += __shfl_xor(sum, 1, 64);
      sum += __shfl_xor(sum, 2, 64);
      sum += __shfl_xor(sum, 4, 64);
      sum += __shfl_xor(sum, 8, 64);
      linv[i][g] = 1.0f / sum;
    }
  }
  __syncthreads();

#pragma unroll
  for (int i = 0; i < 2; ++i)
#pragma unroll
    for (int n = 0; n < 8; ++n)
#pragma unroll
      for (int g = 0; g < 4; ++g) {
        int row = w * 32 + i * 16 + ((lane >> 4) << 2) + g;
        int col = n * 16 + lc;
        Ps[row * 140 + col] = (__bf16)s[i][n][g];
      }
  __syncthreads();

  f32x4 o[2][4];
#pragma unroll
  for (int i = 0; i < 2; ++i)
#pragma unroll
    for (int n = 0; n < 4; ++n) o[i][n] = (f32x4){0.f, 0.f, 0.f, 0.f};
#pragma unroll
  for (int kt = 0; kt < 4; ++kt) {
    bf16x8 a[2];
#pragma unroll
    for (int i = 0; i < 2; ++i)
      a[i] = *(const bf16x8*)&Ps[(w * 32 + i * 16 + lc) * 140 + kt * 32 + q8];
#pragma unroll
    for (int n = 0; n < 4; ++n) {
      bf16x8 b = *(const bf16x8*)&Vt[(n * 16 + lc) * 136 + kt * 32 + q8];
#pragma unroll
      for (int i = 0; i < 2; ++i)
        o[i][n] = __builtin_amdgcn_mfma_f32_16x16x32_bf16(a[i], b, o[i][n], 0, 0, 0);
    }
  }

#pragma unroll
  for (int i = 0; i < 2; ++i)
#pragma unroll
    for (int n = 0; n < 4; ++n)
#pragma unroll
      for (int g = 0; g < 4; ++g) {
        int r = w * 32 + i * 16 + ((lane >> 4) << 2) + g;
        int dh = n * 16 + lc;
        ob[((size_t)(lrel * R_ + r)) * INNER_ + h * 64 + dh] =
            (__bf16)(o[i][n][g] * linv[i][g]);
      }
}

// ---------------------------------------------------------------------------
extern "C" void kernel_launch(void* const* d_in, const int* in_sizes, int n_in,
                              void* d_out, int out_size, void* d_ws,
                              size_t ws_size, hipStream_t stream) {
  (void)in_sizes; (void)n_in; (void)out_size;
  const float* m = (const float*)d_in[0];
  const float* pair = (const float*)d_in[1];
  const float* Wq_w = (const float*)d_in[2];
  const float* Wkv_w = (const float*)d_in[3];
  const float* Wo_w = (const float*)d_in[4];
  const float* bo_w = (const float*)d_in[5];
  const float* Wq_h = (const float*)d_in[6];
  const float* Wkv_h = (const float*)d_in[7];
  const float* Wo_h = (const float*)d_in[8];
  const float* bo_h = (const float*)d_in[9];
  const float* ln_g = (const float*)d_in[10];
  const float* ln_b = (const float*)d_in[11];
  const float* Wpair = (const float*)d_in[12];
  const float* Wsq = (const float*)d_in[13];
  const float* bsq = (const float*)d_in[14];
  const float* Wsk = (const float*)d_in[15];
  const float* bsk = (const float*)d_in[16];
  float* out = (float*)d_out;

  // ---- choose chunking (CH) and split count (S = 8/CH) to fit workspace ----
  const size_t fixedBase = 22446080u;  // everything before dotsP (bytes)
  int CH = 1;
  for (; CH < 8; CH *= 2) {
    size_t partials = (size_t)(8 / CH) * 4718592u;
    size_t o = 201326592u / CH;
    if (o < 25165824u) o = 25165824u;
    if (fixedBase + partials + o <= ws_size) break;
  }
  const int S = 8 / CH;
  const int Lc = L_ / CH;
  const int Rc = R_ / CH;

  unsigned char* base = (unsigned char*)d_ws;
  __bf16* m_bf = (__bf16*)base;       base += 12582912;
  __bf16* WTw = (__bf16*)base;        base += 393216;
  __bf16* WThqk = (__bf16*)base;      base += 262144;
  __bf16* WTvh = (__bf16*)base;       base += 131072;
  __bf16* WoTw = (__bf16*)base;       base += 131072;
  __bf16* WoTh = (__bf16*)base;       base += 131072;
  __bf16* WskT = (__bf16*)base;       base += 32768;
  __bf16* WsqT = (__bf16*)base;       base += 32768;
  float* wtie = (float*)base;         base += 1572864;
  float* pb = (float*)base;           base += 4718592;
  __bf16* attnb = (__bf16*)base;      base += 2359296;
  __bf16* qsb = (__bf16*)base;        base += 98304;
  float* dotsP = (float*)base;        base += (size_t)S * 4718592u;
  unsigned char* ovl = base;
  __bf16* ksb = (__bf16*)ovl;  // (R*L,128) bf16, phase A only

  const size_t BUF = 25165824u / CH;
  __bf16* qb = (__bf16*)ovl;
  __bf16* kb = qb + BUF;
  __bf16* vb = kb + BUF;
  __bf16* ob = vb + BUF;

  cvt_kernel<<<3072, 256, 0, stream>>>(m, m_bf, 786432);
  wt_kernel<<<dim3(8, 2), 256, 0, stream>>>(Wq_w, WTw, 128, 512, 0);
  wt_kernel<<<dim3(16, 2), 256, 0, stream>>>(Wkv_w, WTw + 512 * 128, 128, 1024, 0);
  wt_kernel<<<dim3(8, 2), 256, 0, stream>>>(Wq_h, WThqk, 128, 512, 0);
  wt_kernel<<<dim3(8, 2), 256, 0, stream>>>(Wkv_h, WThqk + 512 * 128, 128, 1024, 0);
  wt_kernel<<<dim3(8, 2), 256, 0, stream>>>(Wkv_h, WTvh, 128, 1024, 512);
  wt_kernel<<<dim3(2, 8), 256, 0, stream>>>(Wo_w, WoTw, 512, 128, 0);
  wt_kernel<<<dim3(2, 8), 256, 0, stream>>>(Wo_h, WoTh, 512, 128, 0);
  wt_kernel<<<dim3(2, 2), 256, 0, stream>>>(Wsk, WskT, 128, 128, 0);
  wt_kernel<<<dim3(2, 2), 256, 0, stream>>>(Wsq, WsqT, 128, 128, 0);

  // tie projections (MFMA) + tie softmax + pair bias
  mm_k<7><<<dim3(1, 384), 256, 0, stream>>>(m_bf, WskT, bsk, nullptr, ksb, nullptr,
                                            nullptr, nullptr, 128, 0, Rc, 0, 0, 1);
  mm_k<7><<<dim3(1, 3), 256, 0, stream>>>(m_bf, WsqT, bsq, nullptr, qsb, nullptr,
                                          nullptr, nullptr, 128, 0, Rc, 0, 0, 1);
  tie_kernel<<<L_ * H_, 128, 0, stream>>>(qsb, ksb, wtie);
  lnpb_kernel<<<(L_ * L_) / 256, 256, 0, stream>>>(pair, ln_g, ln_b, Wpair, pb);

  for (int c = 0; c < CH; ++c) {
    int l0 = c * Lc;
    mm_k<0><<<dim3(12, Lc), 256, 0, stream>>>(m_bf, WTw, nullptr, nullptr, qb, kb, vb,
                                              nullptr, 128, l0, Rc, 0, 0, 1);
    attw_kernel<<<Lc * H_, 256, 0, stream>>>(qb, kb, vb, ob);
    mm_k<4><<<dim3(1, Lc), 256, 0, stream>>>(ob, WoTw, bo_w, nullptr, nullptr, nullptr,
                                             nullptr, out, 512, l0, Rc, 0, 0, 1);
  }

  for (int c = 0; c < CH; ++c) {
    int r0 = c * Rc;
    mm_k<1><<<dim3(8, Rc * 3), 256, 0, stream>>>(m_bf, WThqk, nullptr, nullptr, qb, kb,
                                                 nullptr, nullptr, 128, r0, Rc, 0, 0, 1);
    mm_k<2><<<dim3(3, 3, H_ * S), 256, 0, stream>>>(qb, kb, nullptr, wtie, nullptr,
                                                    nullptr, nullptr, dotsP,
                                                    (Rc * 64) / S, r0, Rc, Rc * 64,
                                                    (c == 0) ? 1 : 0, S);
  }
  sm_kernel<<<H_ * L_, 128, 0, stream>>>(pb, dotsP, S, attnb);

  for (int c = 0; c < CH; ++c) {
    int r0 = c * Rc;
    mm_k<6><<<dim3(3, 4, Rc), 256, 0, stream>>>(WTvh, m_bf, nullptr, nullptr, vb, nullptr,
                                                nullptr, nullptr, 128, r0, Rc, 0, 0, 1);
    mm_k<3><<<dim3(Rc / 2, 3, 8), 256, 0, stream>>>(attnb, vb, nullptr, nullptr, ob, nullptr,
                                                    nullptr, nullptr, 384, r0, Rc, 0, 0, 1);
    mm_k<5><<<dim3(1, Rc * 3), 256, 0, stream>>>(ob, WoTh, bo_h, nullptr, nullptr, nullptr,
                                                 nullptr, out, 512, r0, Rc, 0, 0, 1);
  }
}